// Round 1
// baseline (560.304 us; speedup 1.0000x reference)
//
#include <hip/hip_runtime.h>
#include <hip/hip_bf16.h>
#include <math.h>

#define N_NODES 40000
#define N_EDGES 640000
#define D 128
#define N_GRAPHS 128

typedef __attribute__((ext_vector_type(8))) short bf16x8;
typedef __attribute__((ext_vector_type(4))) float f32x4;

static __device__ __forceinline__ unsigned short f2b(float f) {
    unsigned int u = __float_as_uint(f);
    unsigned int r = (u + 0x7fffu + ((u >> 16) & 1u)) >> 16;  // RNE
    return (unsigned short)r;
}
static __device__ __forceinline__ float b2f(unsigned short h) {
    return __uint_as_float(((unsigned int)h) << 16);
}

// ---- CSR build -------------------------------------------------------------
__global__ void k_hist(const int* __restrict__ ei, int* __restrict__ counts) {
    int e = blockIdx.x * blockDim.x + threadIdx.x;
    if (e < N_EDGES) atomicAdd(&counts[ei[N_EDGES + e]], 1);
}

// counts_cursor: in = per-node counts, out = row start (cursor); row_ptr filled fully
__global__ void k_scan(int* counts_cursor, int* __restrict__ row_ptr) {
    __shared__ int part[1024];
    int t = threadIdx.x;
    int lo = t * 40;
    int hi = lo + 40;
    if (lo > N_NODES) lo = N_NODES;
    if (hi > N_NODES) hi = N_NODES;
    int s = 0;
    for (int i = lo; i < hi; ++i) s += counts_cursor[i];
    part[t] = s;
    __syncthreads();
    for (int off = 1; off < 1024; off <<= 1) {
        int v = (t >= off) ? part[t - off] : 0;
        __syncthreads();
        part[t] += v;
        __syncthreads();
    }
    int run = part[t] - s;  // exclusive prefix
    for (int i = lo; i < hi; ++i) {
        int c = counts_cursor[i];
        row_ptr[i] = run;
        counts_cursor[i] = run;
        run += c;
    }
    if (t == 1023) row_ptr[N_NODES] = part[1023];
}

__global__ void k_scatter(const int* __restrict__ ei, int* __restrict__ cursor,
                          int* __restrict__ src_sorted) {
    int e = blockIdx.x * blockDim.x + threadIdx.x;
    if (e < N_EDGES) {
        int d = ei[N_EDGES + e];
        int pos = atomicAdd(&cursor[d], 1);
        src_sorted[pos] = ei[e];
    }
}

// ---- graph boundaries for segment_max (batch is sorted) --------------------
__global__ void k_bounds(const int* __restrict__ batch, int* __restrict__ bounds) {
    int n = blockIdx.x * blockDim.x + threadIdx.x;
    if (n >= N_NODES) return;
    int b = batch[n];
    if (n == 0) {
        for (int g = 0; g <= b; ++g) bounds[g] = 0;
    } else {
        int pb = batch[n - 1];
        for (int g = pb + 1; g <= b; ++g) bounds[g] = n;
    }
    if (n == N_NODES - 1) {
        for (int g = b + 1; g <= N_GRAPHS; ++g) bounds[g] = N_NODES;
    }
}

// ---- dtype prep ------------------------------------------------------------
__global__ void k_x2b(const float* __restrict__ x, unsigned short* __restrict__ xb) {
    int i = blockIdx.x * blockDim.x + threadIdx.x;
    if (i < N_NODES * D) xb[i] = f2b(x[i]);
}

// WT[c][k] (128 x 256 bf16): k<128 -> W_rel[k][c], k>=128 -> W_root[k-128][c]
__global__ void k_wprep(const float* __restrict__ Wrel, const float* __restrict__ Wroot,
                        unsigned short* __restrict__ WT) {
    int c = blockIdx.x, k = threadIdx.x;
    float v = (k < D) ? Wrel[k * D + c] : Wroot[(k - D) * D + c];
    WT[c * 256 + k] = f2b(v);
}

// ---- per-layer: CSR gather-sum (wave per node) -----------------------------
__global__ void k_aggregate(const unsigned short* __restrict__ in,
                            const int* __restrict__ row_ptr,
                            const int* __restrict__ src_sorted,
                            unsigned short* __restrict__ agg) {
    int node = blockIdx.x * 4 + (threadIdx.x >> 6);
    int lane = threadIdx.x & 63;
    int s = row_ptr[node];
    int e = row_ptr[node + 1];
    const unsigned int* inu = (const unsigned int*)in;
    float a0 = 0.f, a1 = 0.f;
    for (int j = s; j < e; ++j) {
        int sn = src_sorted[j];
        unsigned int v = inu[sn * 64 + lane];
        a0 += __uint_as_float(v << 16);         // even feature (low bf16)
        a1 += __uint_as_float(v & 0xffff0000u); // odd feature (high bf16)
    }
    unsigned int o = ((unsigned int)f2b(a1) << 16) | (unsigned int)f2b(a0);
    ((unsigned int*)agg)[node * 64 + lane] = o;
}

// ---- per-layer MFMA GEMM: out = [agg|in] @ [W_rel;W_root] + b (relu opt) ---
// block: 16 nodes x 128 cols, 4 waves; wave w -> cols [w*32, w*32+32)
__global__ void __launch_bounds__(256) k_gemm(
    const unsigned short* __restrict__ A,   // agg  [N][128] bf16
    const unsigned short* __restrict__ X,   // in   [N][128] bf16
    const unsigned short* __restrict__ WT,  // [128][256] bf16 (k contiguous)
    const float* __restrict__ bias,
    unsigned short* __restrict__ out,       // [N][128] bf16
    int relu) {
    int tid = threadIdx.x;
    int w = tid >> 6;
    int l = tid & 63;
    int row = l & 15, quad = l >> 4;
    int nodebase = blockIdx.x * 16;
    int colbase = w * 32;

    f32x4 acc0 = {0.f, 0.f, 0.f, 0.f};
    f32x4 acc1 = {0.f, 0.f, 0.f, 0.f};

    const short* Ap = (const short*)(A + (nodebase + row) * D);
    const short* Xp = (const short*)(X + (nodebase + row) * D);
    const short* W0 = (const short*)(WT + (colbase + row) * 256);
    const short* W1 = (const short*)(WT + (colbase + 16 + row) * 256);

#pragma unroll
    for (int s = 0; s < 4; ++s) {
        int k0 = s * 32 + quad * 8;
        bf16x8 af = *(const bf16x8*)(Ap + k0);
        bf16x8 b0 = *(const bf16x8*)(W0 + k0);
        bf16x8 b1 = *(const bf16x8*)(W1 + k0);
        acc0 = __builtin_amdgcn_mfma_f32_16x16x32_bf16(af, b0, acc0, 0, 0, 0);
        acc1 = __builtin_amdgcn_mfma_f32_16x16x32_bf16(af, b1, acc1, 0, 0, 0);
    }
#pragma unroll
    for (int s = 0; s < 4; ++s) {
        int k0 = s * 32 + quad * 8;
        bf16x8 xf = *(const bf16x8*)(Xp + k0);
        bf16x8 b0 = *(const bf16x8*)(W0 + 128 + k0);
        bf16x8 b1 = *(const bf16x8*)(W1 + 128 + k0);
        acc0 = __builtin_amdgcn_mfma_f32_16x16x32_bf16(xf, b0, acc0, 0, 0, 0);
        acc1 = __builtin_amdgcn_mfma_f32_16x16x32_bf16(xf, b1, acc1, 0, 0, 0);
    }

    int c0 = colbase + row, c1 = c0 + 16;
    float bia0 = bias[c0], bia1 = bias[c1];
#pragma unroll
    for (int r = 0; r < 4; ++r) {
        int n2 = nodebase + quad * 4 + r;   // D row = quad*4 + r
        float v0 = acc0[r] + bia0;
        float v1 = acc1[r] + bia1;
        if (relu) { v0 = fmaxf(v0, 0.f); v1 = fmaxf(v1, 0.f); }
        out[n2 * D + c0] = f2b(v0);
        out[n2 * D + c1] = f2b(v1);
    }
}

// ---- segment_max over sorted batch ----------------------------------------
__global__ void k_segmax(const unsigned short* __restrict__ h,
                         const int* __restrict__ bounds,
                         float* __restrict__ out) {
    int g = blockIdx.x;
    int c = threadIdx.x;
    int s = bounds[g], e = bounds[g + 1];
    float m0 = -INFINITY, m1 = -INFINITY, m2 = -INFINITY, m3 = -INFINITY;
    int n = s;
    for (; n + 4 <= e; n += 4) {
        m0 = fmaxf(m0, b2f(h[(n + 0) * D + c]));
        m1 = fmaxf(m1, b2f(h[(n + 1) * D + c]));
        m2 = fmaxf(m2, b2f(h[(n + 2) * D + c]));
        m3 = fmaxf(m3, b2f(h[(n + 3) * D + c]));
    }
    for (; n < e; ++n) m0 = fmaxf(m0, b2f(h[n * D + c]));
    out[g * D + c] = fmaxf(fmaxf(m0, m1), fmaxf(m2, m3));
}

extern "C" void kernel_launch(void* const* d_in, const int* in_sizes, int n_in,
                              void* d_out, int out_size, void* d_ws, size_t ws_size,
                              hipStream_t stream) {
    const float* x = (const float*)d_in[0];
    const int* ei = (const int*)d_in[1];
    const int* batch = (const int*)d_in[2];
    const float* Wrel[3]  = {(const float*)d_in[3], (const float*)d_in[6], (const float*)d_in[9]};
    const float* brel[3]  = {(const float*)d_in[4], (const float*)d_in[7], (const float*)d_in[10]};
    const float* Wroot[3] = {(const float*)d_in[5], (const float*)d_in[8], (const float*)d_in[11]};
    float* out = (float*)d_out;

    char* ws = (char*)d_ws;
    size_t off = 0;
    auto alloc = [&](size_t bytes) -> void* {
        void* p = ws + off;
        off = (off + bytes + 255) & ~(size_t)255;
        return p;
    };
    unsigned short* xb  = (unsigned short*)alloc((size_t)N_NODES * D * 2);
    unsigned short* agg = (unsigned short*)alloc((size_t)N_NODES * D * 2);
    unsigned short* hA  = (unsigned short*)alloc((size_t)N_NODES * D * 2);
    unsigned short* hB  = (unsigned short*)alloc((size_t)N_NODES * D * 2);
    unsigned short* WT  = (unsigned short*)alloc((size_t)3 * 128 * 256 * 2);
    int* row_ptr    = (int*)alloc((size_t)(N_NODES + 1) * 4);
    int* cursor     = (int*)alloc((size_t)N_NODES * 4);
    int* src_sorted = (int*)alloc((size_t)N_EDGES * 4);
    int* bounds     = (int*)alloc((size_t)(N_GRAPHS + 1) * 4);

    // CSR build (reused for all 3 layers)
    hipMemsetAsync(cursor, 0, (size_t)N_NODES * 4, stream);
    k_hist<<<(N_EDGES + 255) / 256, 256, 0, stream>>>(ei, cursor);
    k_scan<<<1, 1024, 0, stream>>>(cursor, row_ptr);
    k_scatter<<<(N_EDGES + 255) / 256, 256, 0, stream>>>(ei, cursor, src_sorted);
    k_bounds<<<(N_NODES + 255) / 256, 256, 0, stream>>>(batch, bounds);

    // dtype prep
    k_x2b<<<(N_NODES * D + 255) / 256, 256, 0, stream>>>(x, xb);
    for (int l = 0; l < 3; ++l)
        k_wprep<<<128, 256, 0, stream>>>(Wrel[l], Wroot[l], WT + (size_t)l * 128 * 256);

    // 3 GraphConv layers
    const unsigned short* in = xb;
    unsigned short* houts[3] = {hA, hB, hA};
    for (int l = 0; l < 3; ++l) {
        k_aggregate<<<N_NODES / 4, 256, 0, stream>>>(in, row_ptr, src_sorted, agg);
        k_gemm<<<N_NODES / 16, 256, 0, stream>>>(agg, in, WT + (size_t)l * 128 * 256,
                                                 brel[l], houts[l], (l < 2) ? 1 : 0);
        in = houts[l];
    }

    // global max pool
    k_segmax<<<N_GRAPHS, 128, 0, stream>>>(houts[2], bounds, out);
}

// Round 2
// 474.911 us; speedup vs baseline: 1.1798x; 1.1798x over previous
//
#include <hip/hip_runtime.h>
#include <hip/hip_bf16.h>
#include <math.h>

#define N_NODES 40000
#define N_EDGES 640000
#define D 128
#define N_GRAPHS 128
#define SCAN_NBLK ((N_NODES + 255) / 256)   // 157

typedef __attribute__((ext_vector_type(8))) short bf16x8;
typedef __attribute__((ext_vector_type(4))) float f32x4;

static __device__ __forceinline__ unsigned short f2b(float f) {
    unsigned int u = __float_as_uint(f);
    unsigned int r = (u + 0x7fffu + ((u >> 16) & 1u)) >> 16;  // RNE
    return (unsigned short)r;
}
static __device__ __forceinline__ float b2f(unsigned short h) {
    return __uint_as_float(((unsigned int)h) << 16);
}

// ---- CSR build -------------------------------------------------------------
__global__ void k_hist(const int* __restrict__ ei, int* __restrict__ counts) {
    int e = blockIdx.x * blockDim.x + threadIdx.x;
    if (e < N_EDGES) atomicAdd(&counts[ei[N_EDGES + e]], 1);
}

// Parallel 3-phase exclusive scan of 40K counts.
// Phase 1: per-block scan -> local exclusive prefix + block sum.
__global__ void __launch_bounds__(256) k_scan1(const int* __restrict__ counts,
                                               int* __restrict__ local_pre,
                                               int* __restrict__ blocksums) {
    int t = threadIdx.x;
    int i = blockIdx.x * 256 + t;
    int lane = t & 63, wave = t >> 6;
    int v = (i < N_NODES) ? counts[i] : 0;
    int incl = v;
#pragma unroll
    for (int off = 1; off < 64; off <<= 1) {
        int u = __shfl_up(incl, off);
        if (lane >= off) incl += u;
    }
    __shared__ int ws[4];
    if (lane == 63) ws[wave] = incl;
    __syncthreads();
    int base = 0;
    for (int w = 0; w < 4; ++w) {
        int s = ws[w];
        if (w < wave) base += s;
    }
    if (i < N_NODES) local_pre[i] = base + incl - v;  // exclusive within block
    if (t == 255) blocksums[blockIdx.x] = base + incl;
}

// Phase 2: scan the 157 block sums (one block).
__global__ void __launch_bounds__(256) k_scan2(int* __restrict__ blocksums) {
    int t = threadIdx.x;
    int lane = t & 63, wave = t >> 6;
    int v = (t < SCAN_NBLK) ? blocksums[t] : 0;
    int incl = v;
#pragma unroll
    for (int off = 1; off < 64; off <<= 1) {
        int u = __shfl_up(incl, off);
        if (lane >= off) incl += u;
    }
    __shared__ int ws[4];
    if (lane == 63) ws[wave] = incl;
    __syncthreads();
    int base = 0;
    for (int w = 0; w < 4; ++w) {
        int s = ws[w];
        if (w < wave) base += s;
    }
    if (t < SCAN_NBLK) blocksums[t] = base + incl - v;  // exclusive
}

// Phase 3: global row starts -> row_ptr + cursor.
__global__ void __launch_bounds__(256) k_scan3(const int* __restrict__ local_pre,
                                               const int* __restrict__ blocksums,
                                               int* __restrict__ row_ptr,
                                               int* __restrict__ cursor) {
    int i = blockIdx.x * 256 + threadIdx.x;
    if (i < N_NODES) {
        int rp = blocksums[blockIdx.x] + local_pre[i];
        row_ptr[i] = rp;
        cursor[i] = rp;
    }
    if (i == 0) row_ptr[N_NODES] = N_EDGES;
}

__global__ void k_scatter(const int* __restrict__ ei, int* __restrict__ cursor,
                          int* __restrict__ src_sorted) {
    int e = blockIdx.x * blockDim.x + threadIdx.x;
    if (e < N_EDGES) {
        int d = ei[N_EDGES + e];
        int pos = atomicAdd(&cursor[d], 1);
        src_sorted[pos] = ei[e];
    }
}

// ---- graph boundaries for segment_max (batch is sorted) --------------------
__global__ void k_bounds(const int* __restrict__ batch, int* __restrict__ bounds) {
    int n = blockIdx.x * blockDim.x + threadIdx.x;
    if (n >= N_NODES) return;
    int b = batch[n];
    if (n == 0) {
        for (int g = 0; g <= b; ++g) bounds[g] = 0;
    } else {
        int pb = batch[n - 1];
        for (int g = pb + 1; g <= b; ++g) bounds[g] = n;
    }
    if (n == N_NODES - 1) {
        for (int g = b + 1; g <= N_GRAPHS; ++g) bounds[g] = N_NODES;
    }
}

// ---- dtype prep ------------------------------------------------------------
__global__ void k_x2b(const float* __restrict__ x, unsigned short* __restrict__ xb) {
    int i = blockIdx.x * blockDim.x + threadIdx.x;
    if (i < N_NODES * D) xb[i] = f2b(x[i]);
}

// WT[c][k] (128 x 256 bf16): k<128 -> W_rel[k][c], k>=128 -> W_root[k-128][c]
__global__ void k_wprep(const float* __restrict__ Wrel, const float* __restrict__ Wroot,
                        unsigned short* __restrict__ WT) {
    int c = blockIdx.x, k = threadIdx.x;
    float v = (k < D) ? Wrel[k * D + c] : Wroot[(k - D) * D + c];
    WT[c * 256 + k] = f2b(v);
}

// ---- per-layer: CSR gather-sum (wave per node) -----------------------------
__global__ void k_aggregate(const unsigned short* __restrict__ in,
                            const int* __restrict__ row_ptr,
                            const int* __restrict__ src_sorted,
                            unsigned short* __restrict__ agg) {
    int node = blockIdx.x * 4 + (threadIdx.x >> 6);
    int lane = threadIdx.x & 63;
    int s = row_ptr[node];
    int e = row_ptr[node + 1];
    const unsigned int* inu = (const unsigned int*)in;
    float a0 = 0.f, a1 = 0.f;
    for (int j = s; j < e; ++j) {
        int sn = src_sorted[j];
        unsigned int v = inu[sn * 64 + lane];
        a0 += __uint_as_float(v << 16);         // even feature (low bf16)
        a1 += __uint_as_float(v & 0xffff0000u); // odd feature (high bf16)
    }
    unsigned int o = ((unsigned int)f2b(a1) << 16) | (unsigned int)f2b(a0);
    ((unsigned int*)agg)[node * 64 + lane] = o;
}

// ---- per-layer MFMA GEMM: out = [agg|in] @ [W_rel;W_root] + b (relu opt) ---
// block: 16 nodes x 128 cols, 4 waves; wave w -> cols [w*32, w*32+32)
__global__ void __launch_bounds__(256) k_gemm(
    const unsigned short* __restrict__ A,   // agg  [N][128] bf16
    const unsigned short* __restrict__ X,   // in   [N][128] bf16
    const unsigned short* __restrict__ WT,  // [128][256] bf16 (k contiguous)
    const float* __restrict__ bias,
    unsigned short* __restrict__ out,       // [N][128] bf16
    int relu) {
    int tid = threadIdx.x;
    int w = tid >> 6;
    int l = tid & 63;
    int row = l & 15, quad = l >> 4;
    int nodebase = blockIdx.x * 16;
    int colbase = w * 32;

    f32x4 acc0 = {0.f, 0.f, 0.f, 0.f};
    f32x4 acc1 = {0.f, 0.f, 0.f, 0.f};

    const short* Ap = (const short*)(A + (nodebase + row) * D);
    const short* Xp = (const short*)(X + (nodebase + row) * D);
    const short* W0 = (const short*)(WT + (colbase + row) * 256);
    const short* W1 = (const short*)(WT + (colbase + 16 + row) * 256);

#pragma unroll
    for (int s = 0; s < 4; ++s) {
        int k0 = s * 32 + quad * 8;
        bf16x8 af = *(const bf16x8*)(Ap + k0);
        bf16x8 b0 = *(const bf16x8*)(W0 + k0);
        bf16x8 b1 = *(const bf16x8*)(W1 + k0);
        acc0 = __builtin_amdgcn_mfma_f32_16x16x32_bf16(af, b0, acc0, 0, 0, 0);
        acc1 = __builtin_amdgcn_mfma_f32_16x16x32_bf16(af, b1, acc1, 0, 0, 0);
    }
#pragma unroll
    for (int s = 0; s < 4; ++s) {
        int k0 = s * 32 + quad * 8;
        bf16x8 xf = *(const bf16x8*)(Xp + k0);
        bf16x8 b0 = *(const bf16x8*)(W0 + 128 + k0);
        bf16x8 b1 = *(const bf16x8*)(W1 + 128 + k0);
        acc0 = __builtin_amdgcn_mfma_f32_16x16x32_bf16(xf, b0, acc0, 0, 0, 0);
        acc1 = __builtin_amdgcn_mfma_f32_16x16x32_bf16(xf, b1, acc1, 0, 0, 0);
    }

    int c0 = colbase + row, c1 = c0 + 16;
    float bia0 = bias[c0], bia1 = bias[c1];
#pragma unroll
    for (int r = 0; r < 4; ++r) {
        int n2 = nodebase + quad * 4 + r;   // D row = quad*4 + r
        float v0 = acc0[r] + bia0;
        float v1 = acc1[r] + bia1;
        if (relu) { v0 = fmaxf(v0, 0.f); v1 = fmaxf(v1, 0.f); }
        out[n2 * D + c0] = f2b(v0);
        out[n2 * D + c1] = f2b(v1);
    }
}

// ---- segment_max over sorted batch ----------------------------------------
__global__ void k_segmax(const unsigned short* __restrict__ h,
                         const int* __restrict__ bounds,
                         float* __restrict__ out) {
    int g = blockIdx.x;
    int c = threadIdx.x;
    int s = bounds[g], e = bounds[g + 1];
    float m0 = -INFINITY, m1 = -INFINITY, m2 = -INFINITY, m3 = -INFINITY;
    int n = s;
    for (; n + 4 <= e; n += 4) {
        m0 = fmaxf(m0, b2f(h[(n + 0) * D + c]));
        m1 = fmaxf(m1, b2f(h[(n + 1) * D + c]));
        m2 = fmaxf(m2, b2f(h[(n + 2) * D + c]));
        m3 = fmaxf(m3, b2f(h[(n + 3) * D + c]));
    }
    for (; n < e; ++n) m0 = fmaxf(m0, b2f(h[n * D + c]));
    out[g * D + c] = fmaxf(fmaxf(m0, m1), fmaxf(m2, m3));
}

extern "C" void kernel_launch(void* const* d_in, const int* in_sizes, int n_in,
                              void* d_out, int out_size, void* d_ws, size_t ws_size,
                              hipStream_t stream) {
    const float* x = (const float*)d_in[0];
    const int* ei = (const int*)d_in[1];
    const int* batch = (const int*)d_in[2];
    const float* Wrel[3]  = {(const float*)d_in[3], (const float*)d_in[6], (const float*)d_in[9]};
    const float* brel[3]  = {(const float*)d_in[4], (const float*)d_in[7], (const float*)d_in[10]};
    const float* Wroot[3] = {(const float*)d_in[5], (const float*)d_in[8], (const float*)d_in[11]};
    float* out = (float*)d_out;

    char* ws = (char*)d_ws;
    size_t off = 0;
    auto alloc = [&](size_t bytes) -> void* {
        void* p = ws + off;
        off = (off + bytes + 255) & ~(size_t)255;
        return p;
    };
    unsigned short* xb  = (unsigned short*)alloc((size_t)N_NODES * D * 2);
    unsigned short* agg = (unsigned short*)alloc((size_t)N_NODES * D * 2);
    unsigned short* hA  = (unsigned short*)alloc((size_t)N_NODES * D * 2);
    unsigned short* hB  = (unsigned short*)alloc((size_t)N_NODES * D * 2);
    unsigned short* WT  = (unsigned short*)alloc((size_t)3 * 128 * 256 * 2);
    int* row_ptr    = (int*)alloc((size_t)(N_NODES + 1) * 4);
    int* cursor     = (int*)alloc((size_t)N_NODES * 4);
    int* src_sorted = (int*)alloc((size_t)N_EDGES * 4);
    int* bounds     = (int*)alloc((size_t)(N_GRAPHS + 1) * 4);
    int* local_pre  = (int*)alloc((size_t)N_NODES * 4);
    int* blocksums  = (int*)alloc((size_t)SCAN_NBLK * 4);

    // CSR build (reused for all 3 layers)
    hipMemsetAsync(cursor, 0, (size_t)N_NODES * 4, stream);
    k_hist<<<(N_EDGES + 255) / 256, 256, 0, stream>>>(ei, cursor);
    k_scan1<<<SCAN_NBLK, 256, 0, stream>>>(cursor, local_pre, blocksums);
    k_scan2<<<1, 256, 0, stream>>>(blocksums);
    k_scan3<<<SCAN_NBLK, 256, 0, stream>>>(local_pre, blocksums, row_ptr, cursor);
    k_scatter<<<(N_EDGES + 255) / 256, 256, 0, stream>>>(ei, cursor, src_sorted);
    k_bounds<<<(N_NODES + 255) / 256, 256, 0, stream>>>(batch, bounds);

    // dtype prep
    k_x2b<<<(N_NODES * D + 255) / 256, 256, 0, stream>>>(x, xb);
    for (int l = 0; l < 3; ++l)
        k_wprep<<<128, 256, 0, stream>>>(Wrel[l], Wroot[l], WT + (size_t)l * 128 * 256);

    // 3 GraphConv layers
    const unsigned short* in = xb;
    unsigned short* houts[3] = {hA, hB, hA};
    for (int l = 0; l < 3; ++l) {
        k_aggregate<<<N_NODES / 4, 256, 0, stream>>>(in, row_ptr, src_sorted, agg);
        k_gemm<<<N_NODES / 16, 256, 0, stream>>>(agg, in, WT + (size_t)l * 128 * 256,
                                                 brel[l], houts[l], (l < 2) ? 1 : 0);
        in = houts[l];
    }

    // global max pool
    k_segmax<<<N_GRAPHS, 128, 0, stream>>>(houts[2], bounds, out);
}

// Round 3
// 362.721 us; speedup vs baseline: 1.5447x; 1.3093x over previous
//
#include <hip/hip_runtime.h>
#include <hip/hip_bf16.h>
#include <math.h>

#define N_NODES 40000
#define N_EDGES 640000
#define D 128
#define N_GRAPHS 128
#define SCAN_NBLK ((N_NODES + 255) / 256)   // 157

typedef __attribute__((ext_vector_type(8))) short bf16x8;
typedef __attribute__((ext_vector_type(4))) float f32x4;
typedef __attribute__((ext_vector_type(4))) unsigned int u32x4;

static __device__ __forceinline__ unsigned short f2b(float f) {
    unsigned int u = __float_as_uint(f);
    unsigned int r = (u + 0x7fffu + ((u >> 16) & 1u)) >> 16;  // RNE
    return (unsigned short)r;
}
static __device__ __forceinline__ float b2f(unsigned short h) {
    return __uint_as_float(((unsigned int)h) << 16);
}
static __device__ __forceinline__ float blo(unsigned int u) {
    return __uint_as_float(u << 16);
}
static __device__ __forceinline__ float bhi(unsigned int u) {
    return __uint_as_float(u & 0xffff0000u);
}

// ---- CSR build -------------------------------------------------------------
__global__ void k_hist(const int* __restrict__ ei, int* __restrict__ counts) {
    int e = blockIdx.x * blockDim.x + threadIdx.x;
    if (e < N_EDGES) atomicAdd(&counts[ei[N_EDGES + e]], 1);
}

// Parallel 3-phase exclusive scan of 40K counts.
__global__ void __launch_bounds__(256) k_scan1(const int* __restrict__ counts,
                                               int* __restrict__ local_pre,
                                               int* __restrict__ blocksums) {
    int t = threadIdx.x;
    int i = blockIdx.x * 256 + t;
    int lane = t & 63, wave = t >> 6;
    int v = (i < N_NODES) ? counts[i] : 0;
    int incl = v;
#pragma unroll
    for (int off = 1; off < 64; off <<= 1) {
        int u = __shfl_up(incl, off);
        if (lane >= off) incl += u;
    }
    __shared__ int ws[4];
    if (lane == 63) ws[wave] = incl;
    __syncthreads();
    int base = 0;
    for (int w = 0; w < 4; ++w) {
        int s = ws[w];
        if (w < wave) base += s;
    }
    if (i < N_NODES) local_pre[i] = base + incl - v;
    if (t == 255) blocksums[blockIdx.x] = base + incl;
}

__global__ void __launch_bounds__(256) k_scan2(int* __restrict__ blocksums) {
    int t = threadIdx.x;
    int lane = t & 63, wave = t >> 6;
    int v = (t < SCAN_NBLK) ? blocksums[t] : 0;
    int incl = v;
#pragma unroll
    for (int off = 1; off < 64; off <<= 1) {
        int u = __shfl_up(incl, off);
        if (lane >= off) incl += u;
    }
    __shared__ int ws[4];
    if (lane == 63) ws[wave] = incl;
    __syncthreads();
    int base = 0;
    for (int w = 0; w < 4; ++w) {
        int s = ws[w];
        if (w < wave) base += s;
    }
    if (t < SCAN_NBLK) blocksums[t] = base + incl - v;
}

__global__ void __launch_bounds__(256) k_scan3(const int* __restrict__ local_pre,
                                               const int* __restrict__ blocksums,
                                               int* __restrict__ row_ptr,
                                               int* __restrict__ cursor) {
    int i = blockIdx.x * 256 + threadIdx.x;
    if (i < N_NODES) {
        int rp = blocksums[blockIdx.x] + local_pre[i];
        row_ptr[i] = rp;
        cursor[i] = rp;
    }
    if (i == 0) row_ptr[N_NODES] = N_EDGES;
}

__global__ void k_scatter(const int* __restrict__ ei, int* __restrict__ cursor,
                          int* __restrict__ src_sorted) {
    int e = blockIdx.x * blockDim.x + threadIdx.x;
    if (e < N_EDGES) {
        int d = ei[N_EDGES + e];
        int pos = atomicAdd(&cursor[d], 1);
        src_sorted[pos] = ei[e];
    }
}

// ---- graph boundaries for segment_max (batch is sorted) --------------------
__global__ void k_bounds(const int* __restrict__ batch, int* __restrict__ bounds) {
    int n = blockIdx.x * blockDim.x + threadIdx.x;
    if (n >= N_NODES) return;
    int b = batch[n];
    if (n == 0) {
        for (int g = 0; g <= b; ++g) bounds[g] = 0;
    } else {
        int pb = batch[n - 1];
        for (int g = pb + 1; g <= b; ++g) bounds[g] = n;
    }
    if (n == N_NODES - 1) {
        for (int g = b + 1; g <= N_GRAPHS; ++g) bounds[g] = N_NODES;
    }
}

// ---- dtype prep ------------------------------------------------------------
__global__ void k_x2b(const float* __restrict__ x, unsigned short* __restrict__ xb) {
    int i = blockIdx.x * blockDim.x + threadIdx.x;
    if (i < N_NODES * D) xb[i] = f2b(x[i]);
}

// WT[c][k] (128 x 256 bf16): k<128 -> W_rel[k][c], k>=128 -> W_root[k-128][c]
__global__ void k_wprep(const float* __restrict__ Wrel, const float* __restrict__ Wroot,
                        unsigned short* __restrict__ WT) {
    int c = blockIdx.x, k = threadIdx.x;
    float v = (k < D) ? Wrel[k * D + c] : Wroot[(k - D) * D + c];
    WT[c * 256 + k] = f2b(v);
}

// ---- per-layer: CSR gather-sum -------------------------------------------
// One wave per node. Lane = (g, c): g = lane>>4 picks edge j+g, c = lane&15
// picks 16B chunk of the 256B source row. One dwordx4 load moves 4 edges'
// rows per wave; unroll x2 => 8 edges in flight (vs 1 before).
__global__ void __launch_bounds__(256) k_aggregate(
    const unsigned short* __restrict__ in,
    const int* __restrict__ row_ptr,
    const int* __restrict__ src_sorted,
    unsigned short* __restrict__ agg) {
    int node = blockIdx.x * 4 + (threadIdx.x >> 6);
    int lane = threadIdx.x & 63;
    int g = lane >> 4;      // 0..3: edge sub-slot
    int c = lane & 15;      // 0..15: 16B chunk of row
    int s = row_ptr[node];
    int e = row_ptr[node + 1];
    const u32x4* inv = (const u32x4*)in;

    float a0 = 0.f, a1 = 0.f, a2 = 0.f, a3 = 0.f;
    float a4 = 0.f, a5 = 0.f, a6 = 0.f, a7 = 0.f;

    int j = s;
    for (; j + 8 <= e; j += 8) {
        int sn0 = src_sorted[j + g];
        int sn1 = src_sorted[j + 4 + g];
        u32x4 v0 = inv[sn0 * 16 + c];
        u32x4 v1 = inv[sn1 * 16 + c];
        a0 += blo(v0.x); a1 += bhi(v0.x);
        a2 += blo(v0.y); a3 += bhi(v0.y);
        a4 += blo(v0.z); a5 += bhi(v0.z);
        a6 += blo(v0.w); a7 += bhi(v0.w);
        a0 += blo(v1.x); a1 += bhi(v1.x);
        a2 += blo(v1.y); a3 += bhi(v1.y);
        a4 += blo(v1.z); a5 += bhi(v1.z);
        a6 += blo(v1.w); a7 += bhi(v1.w);
    }
    for (; j < e; j += 4) {
        int jj = j + g;
        if (jj < e) {
            int sn = src_sorted[jj];
            u32x4 v = inv[sn * 16 + c];
            a0 += blo(v.x); a1 += bhi(v.x);
            a2 += blo(v.y); a3 += bhi(v.y);
            a4 += blo(v.z); a5 += bhi(v.z);
            a6 += blo(v.w); a7 += bhi(v.w);
        }
    }

    // reduce across the 4 g-groups (lanes differing in bits 4,5)
    a0 += __shfl_xor(a0, 16); a0 += __shfl_xor(a0, 32);
    a1 += __shfl_xor(a1, 16); a1 += __shfl_xor(a1, 32);
    a2 += __shfl_xor(a2, 16); a2 += __shfl_xor(a2, 32);
    a3 += __shfl_xor(a3, 16); a3 += __shfl_xor(a3, 32);
    a4 += __shfl_xor(a4, 16); a4 += __shfl_xor(a4, 32);
    a5 += __shfl_xor(a5, 16); a5 += __shfl_xor(a5, 32);
    a6 += __shfl_xor(a6, 16); a6 += __shfl_xor(a6, 32);
    a7 += __shfl_xor(a7, 16); a7 += __shfl_xor(a7, 32);

    // lane (g,c) stores uint index c*4+g  <=> feats c*8+2g, c*8+2g+1
    float lo_f, hi_f;
    if (g == 0)      { lo_f = a0; hi_f = a1; }
    else if (g == 1) { lo_f = a2; hi_f = a3; }
    else if (g == 2) { lo_f = a4; hi_f = a5; }
    else             { lo_f = a6; hi_f = a7; }
    unsigned int o = ((unsigned int)f2b(hi_f) << 16) | (unsigned int)f2b(lo_f);
    ((unsigned int*)agg)[node * 64 + c * 4 + g] = o;
}

// ---- per-layer MFMA GEMM: out = [agg|in] @ [W_rel;W_root] + b (relu opt) ---
__global__ void __launch_bounds__(256) k_gemm(
    const unsigned short* __restrict__ A,   // agg  [N][128] bf16
    const unsigned short* __restrict__ X,   // in   [N][128] bf16
    const unsigned short* __restrict__ WT,  // [128][256] bf16 (k contiguous)
    const float* __restrict__ bias,
    unsigned short* __restrict__ out,       // [N][128] bf16
    int relu) {
    int tid = threadIdx.x;
    int w = tid >> 6;
    int l = tid & 63;
    int row = l & 15, quad = l >> 4;
    int nodebase = blockIdx.x * 16;
    int colbase = w * 32;

    f32x4 acc0 = {0.f, 0.f, 0.f, 0.f};
    f32x4 acc1 = {0.f, 0.f, 0.f, 0.f};

    const short* Ap = (const short*)(A + (nodebase + row) * D);
    const short* Xp = (const short*)(X + (nodebase + row) * D);
    const short* W0 = (const short*)(WT + (colbase + row) * 256);
    const short* W1 = (const short*)(WT + (colbase + 16 + row) * 256);

#pragma unroll
    for (int s = 0; s < 4; ++s) {
        int k0 = s * 32 + quad * 8;
        bf16x8 af = *(const bf16x8*)(Ap + k0);
        bf16x8 b0 = *(const bf16x8*)(W0 + k0);
        bf16x8 b1 = *(const bf16x8*)(W1 + k0);
        acc0 = __builtin_amdgcn_mfma_f32_16x16x32_bf16(af, b0, acc0, 0, 0, 0);
        acc1 = __builtin_amdgcn_mfma_f32_16x16x32_bf16(af, b1, acc1, 0, 0, 0);
    }
#pragma unroll
    for (int s = 0; s < 4; ++s) {
        int k0 = s * 32 + quad * 8;
        bf16x8 xf = *(const bf16x8*)(Xp + k0);
        bf16x8 b0 = *(const bf16x8*)(W0 + 128 + k0);
        bf16x8 b1 = *(const bf16x8*)(W1 + 128 + k0);
        acc0 = __builtin_amdgcn_mfma_f32_16x16x32_bf16(xf, b0, acc0, 0, 0, 0);
        acc1 = __builtin_amdgcn_mfma_f32_16x16x32_bf16(xf, b1, acc1, 0, 0, 0);
    }

    int c0 = colbase + row, c1 = c0 + 16;
    float bia0 = bias[c0], bia1 = bias[c1];
#pragma unroll
    for (int r = 0; r < 4; ++r) {
        int n2 = nodebase + quad * 4 + r;   // D row = quad*4 + r
        float v0 = acc0[r] + bia0;
        float v1 = acc1[r] + bia1;
        if (relu) { v0 = fmaxf(v0, 0.f); v1 = fmaxf(v1, 0.f); }
        out[n2 * D + c0] = f2b(v0);
        out[n2 * D + c1] = f2b(v1);
    }
}

// ---- segment_max over sorted batch ----------------------------------------
__global__ void k_segmax(const unsigned short* __restrict__ h,
                         const int* __restrict__ bounds,
                         float* __restrict__ out) {
    int g = blockIdx.x;
    int c = threadIdx.x;
    int s = bounds[g], e = bounds[g + 1];
    float m0 = -INFINITY, m1 = -INFINITY, m2 = -INFINITY, m3 = -INFINITY;
    int n = s;
    for (; n + 4 <= e; n += 4) {
        m0 = fmaxf(m0, b2f(h[(n + 0) * D + c]));
        m1 = fmaxf(m1, b2f(h[(n + 1) * D + c]));
        m2 = fmaxf(m2, b2f(h[(n + 2) * D + c]));
        m3 = fmaxf(m3, b2f(h[(n + 3) * D + c]));
    }
    for (; n < e; ++n) m0 = fmaxf(m0, b2f(h[n * D + c]));
    out[g * D + c] = fmaxf(fmaxf(m0, m1), fmaxf(m2, m3));
}

extern "C" void kernel_launch(void* const* d_in, const int* in_sizes, int n_in,
                              void* d_out, int out_size, void* d_ws, size_t ws_size,
                              hipStream_t stream) {
    const float* x = (const float*)d_in[0];
    const int* ei = (const int*)d_in[1];
    const int* batch = (const int*)d_in[2];
    const float* Wrel[3]  = {(const float*)d_in[3], (const float*)d_in[6], (const float*)d_in[9]};
    const float* brel[3]  = {(const float*)d_in[4], (const float*)d_in[7], (const float*)d_in[10]};
    const float* Wroot[3] = {(const float*)d_in[5], (const float*)d_in[8], (const float*)d_in[11]};
    float* out = (float*)d_out;

    char* ws = (char*)d_ws;
    size_t off = 0;
    auto alloc = [&](size_t bytes) -> void* {
        void* p = ws + off;
        off = (off + bytes + 255) & ~(size_t)255;
        return p;
    };
    unsigned short* xb  = (unsigned short*)alloc((size_t)N_NODES * D * 2);
    unsigned short* agg = (unsigned short*)alloc((size_t)N_NODES * D * 2);
    unsigned short* hA  = (unsigned short*)alloc((size_t)N_NODES * D * 2);
    unsigned short* hB  = (unsigned short*)alloc((size_t)N_NODES * D * 2);
    unsigned short* WT  = (unsigned short*)alloc((size_t)3 * 128 * 256 * 2);
    int* row_ptr    = (int*)alloc((size_t)(N_NODES + 1) * 4);
    int* cursor     = (int*)alloc((size_t)N_NODES * 4);
    int* src_sorted = (int*)alloc((size_t)N_EDGES * 4);
    int* bounds     = (int*)alloc((size_t)(N_GRAPHS + 1) * 4);
    int* local_pre  = (int*)alloc((size_t)N_NODES * 4);
    int* blocksums  = (int*)alloc((size_t)SCAN_NBLK * 4);

    // CSR build (reused for all 3 layers)
    hipMemsetAsync(cursor, 0, (size_t)N_NODES * 4, stream);
    k_hist<<<(N_EDGES + 255) / 256, 256, 0, stream>>>(ei, cursor);
    k_scan1<<<SCAN_NBLK, 256, 0, stream>>>(cursor, local_pre, blocksums);
    k_scan2<<<1, 256, 0, stream>>>(blocksums);
    k_scan3<<<SCAN_NBLK, 256, 0, stream>>>(local_pre, blocksums, row_ptr, cursor);
    k_scatter<<<(N_EDGES + 255) / 256, 256, 0, stream>>>(ei, cursor, src_sorted);
    k_bounds<<<(N_NODES + 255) / 256, 256, 0, stream>>>(batch, bounds);

    // dtype prep
    k_x2b<<<(N_NODES * D + 255) / 256, 256, 0, stream>>>(x, xb);
    for (int l = 0; l < 3; ++l)
        k_wprep<<<128, 256, 0, stream>>>(Wrel[l], Wroot[l], WT + (size_t)l * 128 * 256);

    // 3 GraphConv layers
    const unsigned short* in = xb;
    unsigned short* houts[3] = {hA, hB, hA};
    for (int l = 0; l < 3; ++l) {
        k_aggregate<<<N_NODES / 4, 256, 0, stream>>>(in, row_ptr, src_sorted, agg);
        k_gemm<<<N_NODES / 16, 256, 0, stream>>>(agg, in, WT + (size_t)l * 128 * 256,
                                                 brel[l], houts[l], (l < 2) ? 1 : 0);
        in = houts[l];
    }

    // global max pool
    k_segmax<<<N_GRAPHS, 128, 0, stream>>>(houts[2], bounds, out);
}

// Round 4
// 313.831 us; speedup vs baseline: 1.7854x; 1.1558x over previous
//
#include <hip/hip_runtime.h>
#include <hip/hip_bf16.h>
#include <math.h>

#define N_NODES 40000
#define N_EDGES 640000
#define D 128
#define N_GRAPHS 128
#define SCAN_NBLK ((N_NODES + 255) / 256)   // 157
#define LDS_STRIDE 68                        // words per agg row; 68%32=4 -> 8 words/bank (optimal) on b128 reads

typedef __attribute__((ext_vector_type(8))) short bf16x8;
typedef __attribute__((ext_vector_type(4))) float f32x4;
typedef __attribute__((ext_vector_type(4))) unsigned int u32x4;

static __device__ __forceinline__ unsigned short f2b(float f) {
    unsigned int u = __float_as_uint(f);
    unsigned int r = (u + 0x7fffu + ((u >> 16) & 1u)) >> 16;  // RNE
    return (unsigned short)r;
}
static __device__ __forceinline__ float b2f(unsigned short h) {
    return __uint_as_float(((unsigned int)h) << 16);
}
static __device__ __forceinline__ float blo(unsigned int u) {
    return __uint_as_float(u << 16);
}
static __device__ __forceinline__ float bhi(unsigned int u) {
    return __uint_as_float(u & 0xffff0000u);
}

// ---- CSR build -------------------------------------------------------------
__global__ void k_hist(const int* __restrict__ ei, int* __restrict__ counts) {
    int e = blockIdx.x * blockDim.x + threadIdx.x;
    if (e < N_EDGES) atomicAdd(&counts[ei[N_EDGES + e]], 1);
}

__global__ void __launch_bounds__(256) k_scan1(const int* __restrict__ counts,
                                               int* __restrict__ local_pre,
                                               int* __restrict__ blocksums) {
    int t = threadIdx.x;
    int i = blockIdx.x * 256 + t;
    int lane = t & 63, wave = t >> 6;
    int v = (i < N_NODES) ? counts[i] : 0;
    int incl = v;
#pragma unroll
    for (int off = 1; off < 64; off <<= 1) {
        int u = __shfl_up(incl, off);
        if (lane >= off) incl += u;
    }
    __shared__ int ws[4];
    if (lane == 63) ws[wave] = incl;
    __syncthreads();
    int base = 0;
    for (int w = 0; w < 4; ++w) {
        int s = ws[w];
        if (w < wave) base += s;
    }
    if (i < N_NODES) local_pre[i] = base + incl - v;
    if (t == 255) blocksums[blockIdx.x] = base + incl;
}

__global__ void __launch_bounds__(256) k_scan2(int* __restrict__ blocksums) {
    int t = threadIdx.x;
    int lane = t & 63, wave = t >> 6;
    int v = (t < SCAN_NBLK) ? blocksums[t] : 0;
    int incl = v;
#pragma unroll
    for (int off = 1; off < 64; off <<= 1) {
        int u = __shfl_up(incl, off);
        if (lane >= off) incl += u;
    }
    __shared__ int ws[4];
    if (lane == 63) ws[wave] = incl;
    __syncthreads();
    int base = 0;
    for (int w = 0; w < 4; ++w) {
        int s = ws[w];
        if (w < wave) base += s;
    }
    if (t < SCAN_NBLK) blocksums[t] = base + incl - v;
}

__global__ void __launch_bounds__(256) k_scan3(const int* __restrict__ local_pre,
                                               const int* __restrict__ blocksums,
                                               int* __restrict__ row_ptr,
                                               int* __restrict__ cursor) {
    int i = blockIdx.x * 256 + threadIdx.x;
    if (i < N_NODES) {
        int rp = blocksums[blockIdx.x] + local_pre[i];
        row_ptr[i] = rp;
        cursor[i] = rp;
    }
    if (i == 0) row_ptr[N_NODES] = N_EDGES;
}

__global__ void k_scatter(const int* __restrict__ ei, int* __restrict__ cursor,
                          int* __restrict__ src_sorted) {
    int e = blockIdx.x * blockDim.x + threadIdx.x;
    if (e < N_EDGES) {
        int d = ei[N_EDGES + e];
        int pos = atomicAdd(&cursor[d], 1);
        src_sorted[pos] = ei[e];
    }
}

// ---- graph boundaries for segment_max (batch is sorted) --------------------
__global__ void k_bounds(const int* __restrict__ batch, int* __restrict__ bounds) {
    int n = blockIdx.x * blockDim.x + threadIdx.x;
    if (n >= N_NODES) return;
    int b = batch[n];
    if (n == 0) {
        for (int g = 0; g <= b; ++g) bounds[g] = 0;
    } else {
        int pb = batch[n - 1];
        for (int g = pb + 1; g <= b; ++g) bounds[g] = n;
    }
    if (n == N_NODES - 1) {
        for (int g = b + 1; g <= N_GRAPHS; ++g) bounds[g] = N_NODES;
    }
}

// ---- dtype prep ------------------------------------------------------------
// 8 floats -> 4 packed bf16-pair uints per thread
__global__ void k_x2b(const float* __restrict__ x, unsigned int* __restrict__ xb) {
    int i = blockIdx.x * blockDim.x + threadIdx.x;   // i < N*D/8
    if (i >= N_NODES * D / 8) return;
    const f32x4* xv = (const f32x4*)x;
    f32x4 v0 = xv[i * 2], v1 = xv[i * 2 + 1];
    u32x4 o;
    o.x = ((unsigned int)f2b(v0.y) << 16) | f2b(v0.x);
    o.y = ((unsigned int)f2b(v0.w) << 16) | f2b(v0.z);
    o.z = ((unsigned int)f2b(v1.y) << 16) | f2b(v1.x);
    o.w = ((unsigned int)f2b(v1.w) << 16) | f2b(v1.z);
    ((u32x4*)xb)[i] = o;
}

// WT[l][c][k] (3 x 128 x 256 bf16): k<128 -> W_rel[k][c], k>=128 -> W_root[k-128][c]
__global__ void k_wprep3(const float* __restrict__ Wr0, const float* __restrict__ Wt0,
                         const float* __restrict__ Wr1, const float* __restrict__ Wt1,
                         const float* __restrict__ Wr2, const float* __restrict__ Wt2,
                         unsigned short* __restrict__ WT) {
    int l = blockIdx.x >> 7, c = blockIdx.x & 127, k = threadIdx.x;
    const float* Wrel = (l == 0) ? Wr0 : (l == 1) ? Wr1 : Wr2;
    const float* Wroot = (l == 0) ? Wt0 : (l == 1) ? Wt1 : Wt2;
    float v = (k < D) ? Wrel[k * D + c] : Wroot[(k - D) * D + c];
    WT[(size_t)l * 128 * 256 + c * 256 + k] = f2b(v);
}

// ---- fused layer: CSR gather-sum (to LDS) + MFMA GEMM ----------------------
// Block = 16 nodes, 4 waves.
// Phase 1: wave w aggregates nodes w*4..w*4+3. Lane=(g,c): g=lane>>4 picks
//   edge j+g, c=lane&15 picks 16B chunk of the 256B source row; 8 edges in
//   flight per trip; shfl-reduce across g; packed bf16 pair -> LDS.
// Phase 2: GEMM out[16][128] = [aggLDS|X] @ [W_rel;W_root] + b. A-fragment
//   lane map (row=lane&15, quad=lane>>4) == phase-1 (c,g) map.
__global__ void __launch_bounds__(256) k_layer(
    const unsigned short* __restrict__ in,  // [N][128] bf16
    const int* __restrict__ row_ptr,
    const int* __restrict__ src_sorted,
    const unsigned short* __restrict__ WT,  // [128][256] bf16 (k contiguous)
    const float* __restrict__ bias,
    unsigned short* __restrict__ out,       // [N][128] bf16
    int relu) {
    __shared__ unsigned int aggLDS[16 * LDS_STRIDE];
    int tid = threadIdx.x;
    int w = tid >> 6;
    int lane = tid & 63;
    int g = lane >> 4;      // edge sub-slot / MFMA quad
    int c = lane & 15;      // 16B chunk / MFMA row
    int nodebase = blockIdx.x * 16;
    const u32x4* inv = (const u32x4*)in;

    // ---- phase 1: aggregate 4 nodes per wave into LDS ----
    for (int q = 0; q < 4; ++q) {
        int nl = w * 4 + q;
        int s = row_ptr[nodebase + nl];
        int e = row_ptr[nodebase + nl + 1];

        float a0 = 0.f, a1 = 0.f, a2 = 0.f, a3 = 0.f;
        float a4 = 0.f, a5 = 0.f, a6 = 0.f, a7 = 0.f;
        int j = s;
        for (; j + 8 <= e; j += 8) {
            int sn0 = src_sorted[j + g];
            int sn1 = src_sorted[j + 4 + g];
            u32x4 v0 = inv[sn0 * 16 + c];
            u32x4 v1 = inv[sn1 * 16 + c];
            a0 += blo(v0.x); a1 += bhi(v0.x);
            a2 += blo(v0.y); a3 += bhi(v0.y);
            a4 += blo(v0.z); a5 += bhi(v0.z);
            a6 += blo(v0.w); a7 += bhi(v0.w);
            a0 += blo(v1.x); a1 += bhi(v1.x);
            a2 += blo(v1.y); a3 += bhi(v1.y);
            a4 += blo(v1.z); a5 += bhi(v1.z);
            a6 += blo(v1.w); a7 += bhi(v1.w);
        }
        for (; j < e; j += 4) {
            int jj = j + g;
            if (jj < e) {
                int sn = src_sorted[jj];
                u32x4 v = inv[sn * 16 + c];
                a0 += blo(v.x); a1 += bhi(v.x);
                a2 += blo(v.y); a3 += bhi(v.y);
                a4 += blo(v.z); a5 += bhi(v.z);
                a6 += blo(v.w); a7 += bhi(v.w);
            }
        }
        a0 += __shfl_xor(a0, 16); a0 += __shfl_xor(a0, 32);
        a1 += __shfl_xor(a1, 16); a1 += __shfl_xor(a1, 32);
        a2 += __shfl_xor(a2, 16); a2 += __shfl_xor(a2, 32);
        a3 += __shfl_xor(a3, 16); a3 += __shfl_xor(a3, 32);
        a4 += __shfl_xor(a4, 16); a4 += __shfl_xor(a4, 32);
        a5 += __shfl_xor(a5, 16); a5 += __shfl_xor(a5, 32);
        a6 += __shfl_xor(a6, 16); a6 += __shfl_xor(a6, 32);
        a7 += __shfl_xor(a7, 16); a7 += __shfl_xor(a7, 32);

        float lo_f, hi_f;
        if (g == 0)      { lo_f = a0; hi_f = a1; }
        else if (g == 1) { lo_f = a2; hi_f = a3; }
        else if (g == 2) { lo_f = a4; hi_f = a5; }
        else             { lo_f = a6; hi_f = a7; }
        unsigned int o = ((unsigned int)f2b(hi_f) << 16) | (unsigned int)f2b(lo_f);
        aggLDS[nl * LDS_STRIDE + c * 4 + g] = o;   // word wc=c*4+g <=> feats c*8+2g,+1
    }
    __syncthreads();

    // ---- phase 2: GEMM ----
    int row = c, quad = g;
    int colbase = w * 32;

    f32x4 acc0 = {0.f, 0.f, 0.f, 0.f};
    f32x4 acc1 = {0.f, 0.f, 0.f, 0.f};

    const unsigned int* Al = &aggLDS[row * LDS_STRIDE];
    const short* Xp = (const short*)(in + (nodebase + row) * D);
    const short* W0 = (const short*)(WT + (colbase + row) * 256);
    const short* W1 = (const short*)(WT + (colbase + 16 + row) * 256);

#pragma unroll
    for (int s = 0; s < 4; ++s) {
        bf16x8 af = *(const bf16x8*)(Al + s * 16 + quad * 4);
        int k0 = s * 32 + quad * 8;
        bf16x8 b0 = *(const bf16x8*)(W0 + k0);
        bf16x8 b1 = *(const bf16x8*)(W1 + k0);
        acc0 = __builtin_amdgcn_mfma_f32_16x16x32_bf16(af, b0, acc0, 0, 0, 0);
        acc1 = __builtin_amdgcn_mfma_f32_16x16x32_bf16(af, b1, acc1, 0, 0, 0);
    }
#pragma unroll
    for (int s = 0; s < 4; ++s) {
        int k0 = s * 32 + quad * 8;
        bf16x8 xf = *(const bf16x8*)(Xp + k0);
        bf16x8 b0 = *(const bf16x8*)(W0 + 128 + k0);
        bf16x8 b1 = *(const bf16x8*)(W1 + 128 + k0);
        acc0 = __builtin_amdgcn_mfma_f32_16x16x32_bf16(xf, b0, acc0, 0, 0, 0);
        acc1 = __builtin_amdgcn_mfma_f32_16x16x32_bf16(xf, b1, acc1, 0, 0, 0);
    }

    int c0 = colbase + row, c1 = c0 + 16;
    float bia0 = bias[c0], bia1 = bias[c1];
#pragma unroll
    for (int r = 0; r < 4; ++r) {
        int n2 = nodebase + quad * 4 + r;
        float v0 = acc0[r] + bia0;
        float v1 = acc1[r] + bia1;
        if (relu) { v0 = fmaxf(v0, 0.f); v1 = fmaxf(v1, 0.f); }
        out[n2 * D + c0] = f2b(v0);
        out[n2 * D + c1] = f2b(v1);
    }
}

// ---- segment_max over sorted batch ----------------------------------------
// 128 blocks x 512 threads: 8 row-groups x 64 uint-cols; u32 loads, x2 unroll.
__global__ void __launch_bounds__(512) k_segmax(const unsigned short* __restrict__ h,
                                                const int* __restrict__ bounds,
                                                float* __restrict__ out) {
    __shared__ float sm[8][128];
    int g = blockIdx.x;
    int tid = threadIdx.x;
    int rg = tid >> 6;      // 0..7
    int c = tid & 63;       // uint col -> feats 2c, 2c+1
    int s = bounds[g], e = bounds[g + 1];
    const unsigned int* h32 = (const unsigned int*)h;

    float m0 = -INFINITY, m1 = -INFINITY;
    int n = s + rg;
    for (; n + 8 < e; n += 16) {
        unsigned int v0 = h32[n * 64 + c];
        unsigned int v1 = h32[(n + 8) * 64 + c];
        m0 = fmaxf(m0, blo(v0)); m1 = fmaxf(m1, bhi(v0));
        m0 = fmaxf(m0, blo(v1)); m1 = fmaxf(m1, bhi(v1));
    }
    if (n < e) {
        unsigned int v0 = h32[n * 64 + c];
        m0 = fmaxf(m0, blo(v0)); m1 = fmaxf(m1, bhi(v0));
    }
    sm[rg][c * 2] = m0;
    sm[rg][c * 2 + 1] = m1;
    __syncthreads();
    if (tid < 128) {
        float m = sm[0][tid];
#pragma unroll
        for (int r = 1; r < 8; ++r) m = fmaxf(m, sm[r][tid]);
        out[g * D + tid] = m;
    }
}

extern "C" void kernel_launch(void* const* d_in, const int* in_sizes, int n_in,
                              void* d_out, int out_size, void* d_ws, size_t ws_size,
                              hipStream_t stream) {
    const float* x = (const float*)d_in[0];
    const int* ei = (const int*)d_in[1];
    const int* batch = (const int*)d_in[2];
    const float* Wrel[3]  = {(const float*)d_in[3], (const float*)d_in[6], (const float*)d_in[9]};
    const float* brel[3]  = {(const float*)d_in[4], (const float*)d_in[7], (const float*)d_in[10]};
    const float* Wroot[3] = {(const float*)d_in[5], (const float*)d_in[8], (const float*)d_in[11]};
    float* out = (float*)d_out;

    char* ws = (char*)d_ws;
    size_t off = 0;
    auto alloc = [&](size_t bytes) -> void* {
        void* p = ws + off;
        off = (off + bytes + 255) & ~(size_t)255;
        return p;
    };
    unsigned short* xb  = (unsigned short*)alloc((size_t)N_NODES * D * 2);
    unsigned short* hA  = (unsigned short*)alloc((size_t)N_NODES * D * 2);
    unsigned short* hB  = (unsigned short*)alloc((size_t)N_NODES * D * 2);
    unsigned short* WT  = (unsigned short*)alloc((size_t)3 * 128 * 256 * 2);
    int* row_ptr    = (int*)alloc((size_t)(N_NODES + 1) * 4);
    int* cursor     = (int*)alloc((size_t)N_NODES * 4);
    int* src_sorted = (int*)alloc((size_t)N_EDGES * 4);
    int* bounds     = (int*)alloc((size_t)(N_GRAPHS + 1) * 4);
    int* local_pre  = (int*)alloc((size_t)N_NODES * 4);
    int* blocksums  = (int*)alloc((size_t)SCAN_NBLK * 4);

    // CSR build (reused for all 3 layers)
    hipMemsetAsync(cursor, 0, (size_t)N_NODES * 4, stream);
    k_hist<<<(N_EDGES + 255) / 256, 256, 0, stream>>>(ei, cursor);
    k_scan1<<<SCAN_NBLK, 256, 0, stream>>>(cursor, local_pre, blocksums);
    k_scan2<<<1, 256, 0, stream>>>(blocksums);
    k_scan3<<<SCAN_NBLK, 256, 0, stream>>>(local_pre, blocksums, row_ptr, cursor);
    k_scatter<<<(N_EDGES + 255) / 256, 256, 0, stream>>>(ei, cursor, src_sorted);
    k_bounds<<<(N_NODES + 255) / 256, 256, 0, stream>>>(batch, bounds);

    // dtype prep
    k_x2b<<<(N_NODES * D / 8 + 255) / 256, 256, 0, stream>>>(x, (unsigned int*)xb);
    k_wprep3<<<384, 256, 0, stream>>>(Wrel[0], Wroot[0], Wrel[1], Wroot[1],
                                      Wrel[2], Wroot[2], WT);

    // 3 fused GraphConv layers
    const unsigned short* in = xb;
    unsigned short* houts[3] = {hA, hB, hA};
    for (int l = 0; l < 3; ++l) {
        k_layer<<<N_NODES / 16, 256, 0, stream>>>(in, row_ptr, src_sorted,
                                                  WT + (size_t)l * 128 * 256,
                                                  brel[l], houts[l], (l < 2) ? 1 : 0);
        in = houts[l];
    }

    // global max pool
    k_segmax<<<N_GRAPHS, 512, 0, stream>>>(houts[2], bounds, out);
}

// Round 5
// 295.555 us; speedup vs baseline: 1.8958x; 1.0618x over previous
//
#include <hip/hip_runtime.h>
#include <hip/hip_bf16.h>
#include <math.h>

#define N_NODES 40000
#define N_EDGES 640000
#define D 128
#define N_GRAPHS 128
#define SCAN_NBLK ((N_NODES + 255) / 256)   // 157
#define LDS_STRIDE 68                        // words per agg row (pad vs 64 to spread banks)

typedef __attribute__((ext_vector_type(8))) short bf16x8;
typedef __attribute__((ext_vector_type(4))) float f32x4;
typedef __attribute__((ext_vector_type(4))) unsigned int u32x4;

static __device__ __forceinline__ unsigned short f2b(float f) {
    unsigned int u = __float_as_uint(f);
    unsigned int r = (u + 0x7fffu + ((u >> 16) & 1u)) >> 16;  // RNE
    return (unsigned short)r;
}
static __device__ __forceinline__ float blo(unsigned int u) {
    return __uint_as_float(u << 16);
}
static __device__ __forceinline__ float bhi(unsigned int u) {
    return __uint_as_float(u & 0xffff0000u);
}

// ---- CSR build (segments padded to multiples of 8) -------------------------
__global__ void k_hist(const int* __restrict__ ei, int* __restrict__ counts) {
    int e = blockIdx.x * blockDim.x + threadIdx.x;
    if (e < N_EDGES) atomicAdd(&counts[ei[N_EDGES + e]], 1);
}

__global__ void __launch_bounds__(256) k_scan1(const int* __restrict__ counts,
                                               int* __restrict__ local_pre,
                                               int* __restrict__ blocksums) {
    int t = threadIdx.x;
    int i = blockIdx.x * 256 + t;
    int lane = t & 63, wave = t >> 6;
    int v = (i < N_NODES) ? ((counts[i] + 7) & ~7) : 0;   // padded degree
    int incl = v;
#pragma unroll
    for (int off = 1; off < 64; off <<= 1) {
        int u = __shfl_up(incl, off);
        if (lane >= off) incl += u;
    }
    __shared__ int ws[4];
    if (lane == 63) ws[wave] = incl;
    __syncthreads();
    int base = 0;
    for (int w = 0; w < 4; ++w) {
        int s = ws[w];
        if (w < wave) base += s;
    }
    if (i < N_NODES) local_pre[i] = base + incl - v;
    if (t == 255) blocksums[blockIdx.x] = base + incl;
}

__global__ void __launch_bounds__(256) k_scan2(int* __restrict__ blocksums) {
    int t = threadIdx.x;
    int lane = t & 63, wave = t >> 6;
    int v = (t < SCAN_NBLK) ? blocksums[t] : 0;
    int incl = v;
#pragma unroll
    for (int off = 1; off < 64; off <<= 1) {
        int u = __shfl_up(incl, off);
        if (lane >= off) incl += u;
    }
    __shared__ int ws[4];
    if (lane == 63) ws[wave] = incl;
    __syncthreads();
    int base = 0;
    for (int w = 0; w < 4; ++w) {
        int s = ws[w];
        if (w < wave) base += s;
    }
    if (t < SCAN_NBLK) blocksums[t] = base + incl - v;
}

__global__ void __launch_bounds__(256) k_scan3(const int* __restrict__ local_pre,
                                               const int* __restrict__ blocksums,
                                               const int* __restrict__ counts,
                                               int* __restrict__ rp_pad,
                                               int* __restrict__ cursor) {
    int i = blockIdx.x * 256 + threadIdx.x;
    if (i < N_NODES) {
        int rp = blocksums[blockIdx.x] + local_pre[i];
        rp_pad[i] = rp;
        cursor[i] = rp;
        if (i == N_NODES - 1) rp_pad[N_NODES] = rp + ((counts[i] + 7) & ~7);
    }
}

__global__ void k_scatter(const int* __restrict__ ei, int* __restrict__ cursor,
                          int* __restrict__ src_pad) {
    int e = blockIdx.x * blockDim.x + threadIdx.x;
    if (e < N_EDGES) {
        int d = ei[N_EDGES + e];
        int pos = atomicAdd(&cursor[d], 1);
        src_pad[pos] = ei[e];
    }
}

// Fill dummy slots [real end, padded end) with N_NODES (the zero row).
__global__ void k_pad(const int* __restrict__ cursor, const int* __restrict__ rp_pad,
                      int* __restrict__ src_pad) {
    int i = blockIdx.x * blockDim.x + threadIdx.x;
    if (i >= N_NODES) return;
    int s = cursor[i], e = rp_pad[i + 1];
    for (int j = s; j < e; ++j) src_pad[j] = N_NODES;
}

// ---- graph boundaries for segment_max (batch is sorted) --------------------
__global__ void k_bounds(const int* __restrict__ batch, int* __restrict__ bounds) {
    int n = blockIdx.x * blockDim.x + threadIdx.x;
    if (n >= N_NODES) return;
    int b = batch[n];
    if (n == 0) {
        for (int g = 0; g <= b; ++g) bounds[g] = 0;
    } else {
        int pb = batch[n - 1];
        for (int g = pb + 1; g <= b; ++g) bounds[g] = n;
    }
    if (n == N_NODES - 1) {
        for (int g = b + 1; g <= N_GRAPHS; ++g) bounds[g] = N_NODES;
    }
}

// ---- dtype prep ------------------------------------------------------------
__global__ void k_x2b(const float* __restrict__ x, unsigned int* __restrict__ xb) {
    int i = blockIdx.x * blockDim.x + threadIdx.x;   // i < N*D/8
    if (i >= N_NODES * D / 8) return;
    const f32x4* xv = (const f32x4*)x;
    f32x4 v0 = xv[i * 2], v1 = xv[i * 2 + 1];
    u32x4 o;
    o.x = ((unsigned int)f2b(v0.y) << 16) | f2b(v0.x);
    o.y = ((unsigned int)f2b(v0.w) << 16) | f2b(v0.z);
    o.z = ((unsigned int)f2b(v1.y) << 16) | f2b(v1.x);
    o.w = ((unsigned int)f2b(v1.w) << 16) | f2b(v1.z);
    ((u32x4*)xb)[i] = o;
}

// WT[l][c][k] (3 x 128 x 256 bf16): k<128 -> W_rel[k][c], k>=128 -> W_root[k-128][c]
__global__ void k_wprep3(const float* __restrict__ Wr0, const float* __restrict__ Wt0,
                         const float* __restrict__ Wr1, const float* __restrict__ Wt1,
                         const float* __restrict__ Wr2, const float* __restrict__ Wt2,
                         unsigned short* __restrict__ WT) {
    int l = blockIdx.x >> 7, c = blockIdx.x & 127, k = threadIdx.x;
    const float* Wrel = (l == 0) ? Wr0 : (l == 1) ? Wr1 : Wr2;
    const float* Wroot = (l == 0) ? Wt0 : (l == 1) ? Wt1 : Wt2;
    float v = (k < D) ? Wrel[k * D + c] : Wroot[(k - D) * D + c];
    WT[(size_t)l * 128 * 256 + c * 256 + k] = f2b(v);
}

// ---- fused layer: CSR gather-sum (to LDS) + MFMA GEMM ----------------------
// Block = 16 nodes, 4 waves. Lane = (q = node slot lane>>4, c = chunk lane&15).
// Phase 1: the 4 nodes of a wave run IN PARALLEL; per trip each 16-lane group
//   reads 8 full rows of its node (group-uniform row index -> one contiguous
//   256B segment per instr), 32 rows in flight per wave. Segments are padded
//   to x8 with the zero row N_NODES -> no tail, aligned int4 index loads.
//   Lane (q,c) accumulates feats [c*8, c*8+8) of node q -> one ds_write_b128.
// Phase 2: GEMM out[16][128] = [aggLDS|X] @ [W_rel;W_root] + b; A-frag lane
//   map (row=lane&15, quad=lane>>4) reads linear-feat LDS rows.
__global__ void __launch_bounds__(256) k_layer(
    const unsigned short* __restrict__ in,  // [N+1][128] bf16 (row N zero)
    const int* __restrict__ rp_pad,
    const int* __restrict__ src_pad,
    const unsigned short* __restrict__ WT,  // [128][256] bf16 (k contiguous)
    const float* __restrict__ bias,
    unsigned short* __restrict__ out,       // [N+1][128] bf16
    int relu) {
    __shared__ unsigned int aggLDS[16 * LDS_STRIDE];
    int tid = threadIdx.x;
    int w = tid >> 6;
    int lane = tid & 63;
    int q = lane >> 4;      // node slot / MFMA quad
    int c = lane & 15;      // 16B chunk / MFMA row
    int nl = w * 4 + q;
    int nodebase = blockIdx.x * 16;
    const u32x4* inv = (const u32x4*)in;

    // ---- phase 1 ----
    int s = rp_pad[nodebase + nl];
    int e = rp_pad[nodebase + nl + 1];
    const int4* sidx = (const int4*)(src_pad + s);
    int ntrips = (e - s) >> 3;

    float a0 = 0.f, a1 = 0.f, a2 = 0.f, a3 = 0.f;
    float a4 = 0.f, a5 = 0.f, a6 = 0.f, a7 = 0.f;

#define ACC8(v) do { \
        a0 += blo((v).x); a1 += bhi((v).x); \
        a2 += blo((v).y); a3 += bhi((v).y); \
        a4 += blo((v).z); a5 += bhi((v).z); \
        a6 += blo((v).w); a7 += bhi((v).w); } while (0)

    for (int t = 0; t < ntrips; ++t) {
        int4 ia = sidx[2 * t];
        int4 ib = sidx[2 * t + 1];
        u32x4 v0 = inv[ia.x * 16 + c];
        u32x4 v1 = inv[ia.y * 16 + c];
        u32x4 v2 = inv[ia.z * 16 + c];
        u32x4 v3 = inv[ia.w * 16 + c];
        u32x4 v4 = inv[ib.x * 16 + c];
        u32x4 v5 = inv[ib.y * 16 + c];
        u32x4 v6 = inv[ib.z * 16 + c];
        u32x4 v7 = inv[ib.w * 16 + c];
        ACC8(v0); ACC8(v1); ACC8(v2); ACC8(v3);
        ACC8(v4); ACC8(v5); ACC8(v6); ACC8(v7);
    }
#undef ACC8

    u32x4 o;
    o.x = ((unsigned int)f2b(a1) << 16) | f2b(a0);
    o.y = ((unsigned int)f2b(a3) << 16) | f2b(a2);
    o.z = ((unsigned int)f2b(a5) << 16) | f2b(a4);
    o.w = ((unsigned int)f2b(a7) << 16) | f2b(a6);
    *(u32x4*)&aggLDS[nl * LDS_STRIDE + c * 4] = o;   // linear feats: word i = feats 2i,2i+1
    __syncthreads();

    // ---- phase 2: GEMM ----
    int row = c, quad = q;
    int colbase = w * 32;

    f32x4 acc0 = {0.f, 0.f, 0.f, 0.f};
    f32x4 acc1 = {0.f, 0.f, 0.f, 0.f};

    const unsigned int* Al = &aggLDS[row * LDS_STRIDE];
    const short* Xp = (const short*)(in + (nodebase + row) * D);
    const short* W0 = (const short*)(WT + (colbase + row) * 256);
    const short* W1 = (const short*)(WT + (colbase + 16 + row) * 256);

#pragma unroll
    for (int t = 0; t < 4; ++t) {
        bf16x8 af = *(const bf16x8*)(Al + t * 16 + quad * 4);
        int k0 = t * 32 + quad * 8;
        bf16x8 b0 = *(const bf16x8*)(W0 + k0);
        bf16x8 b1 = *(const bf16x8*)(W1 + k0);
        acc0 = __builtin_amdgcn_mfma_f32_16x16x32_bf16(af, b0, acc0, 0, 0, 0);
        acc1 = __builtin_amdgcn_mfma_f32_16x16x32_bf16(af, b1, acc1, 0, 0, 0);
    }
#pragma unroll
    for (int t = 0; t < 4; ++t) {
        int k0 = t * 32 + quad * 8;
        bf16x8 xf = *(const bf16x8*)(Xp + k0);
        bf16x8 b0 = *(const bf16x8*)(W0 + 128 + k0);
        bf16x8 b1 = *(const bf16x8*)(W1 + 128 + k0);
        acc0 = __builtin_amdgcn_mfma_f32_16x16x32_bf16(xf, b0, acc0, 0, 0, 0);
        acc1 = __builtin_amdgcn_mfma_f32_16x16x32_bf16(xf, b1, acc1, 0, 0, 0);
    }

    int c0 = colbase + row, c1 = c0 + 16;
    float bia0 = bias[c0], bia1 = bias[c1];
#pragma unroll
    for (int r = 0; r < 4; ++r) {
        int n2 = nodebase + quad * 4 + r;
        float v0 = acc0[r] + bia0;
        float v1 = acc1[r] + bia1;
        if (relu) { v0 = fmaxf(v0, 0.f); v1 = fmaxf(v1, 0.f); }
        out[n2 * D + c0] = f2b(v0);
        out[n2 * D + c1] = f2b(v1);
    }
}

// ---- segment_max over sorted batch ----------------------------------------
__global__ void __launch_bounds__(512) k_segmax(const unsigned short* __restrict__ h,
                                                const int* __restrict__ bounds,
                                                float* __restrict__ out) {
    __shared__ float sm[8][128];
    int g = blockIdx.x;
    int tid = threadIdx.x;
    int rg = tid >> 6;      // 0..7
    int c = tid & 63;       // uint col -> feats 2c, 2c+1
    int s = bounds[g], e = bounds[g + 1];
    const unsigned int* h32 = (const unsigned int*)h;

    float m0 = -INFINITY, m1 = -INFINITY;
    int n = s + rg;
    for (; n + 8 < e; n += 16) {
        unsigned int v0 = h32[n * 64 + c];
        unsigned int v1 = h32[(n + 8) * 64 + c];
        m0 = fmaxf(m0, blo(v0)); m1 = fmaxf(m1, bhi(v0));
        m0 = fmaxf(m0, blo(v1)); m1 = fmaxf(m1, bhi(v1));
    }
    if (n < e) {
        unsigned int v0 = h32[n * 64 + c];
        m0 = fmaxf(m0, blo(v0)); m1 = fmaxf(m1, bhi(v0));
    }
    sm[rg][c * 2] = m0;
    sm[rg][c * 2 + 1] = m1;
    __syncthreads();
    if (tid < 128) {
        float m = sm[0][tid];
#pragma unroll
        for (int r = 1; r < 8; ++r) m = fmaxf(m, sm[r][tid]);
        out[g * D + tid] = m;
    }
}

extern "C" void kernel_launch(void* const* d_in, const int* in_sizes, int n_in,
                              void* d_out, int out_size, void* d_ws, size_t ws_size,
                              hipStream_t stream) {
    const float* x = (const float*)d_in[0];
    const int* ei = (const int*)d_in[1];
    const int* batch = (const int*)d_in[2];
    const float* Wrel[3]  = {(const float*)d_in[3], (const float*)d_in[6], (const float*)d_in[9]};
    const float* brel[3]  = {(const float*)d_in[4], (const float*)d_in[7], (const float*)d_in[10]};
    const float* Wroot[3] = {(const float*)d_in[5], (const float*)d_in[8], (const float*)d_in[11]};
    float* out = (float*)d_out;

    char* ws = (char*)d_ws;
    size_t off = 0;
    auto alloc = [&](size_t bytes) -> void* {
        void* p = ws + off;
        off = (off + bytes + 255) & ~(size_t)255;
        return p;
    };
    // activation buffers have one extra zero row (index N_NODES)
    unsigned short* xb  = (unsigned short*)alloc((size_t)(N_NODES + 1) * D * 2);
    unsigned short* hA  = (unsigned short*)alloc((size_t)(N_NODES + 1) * D * 2);
    unsigned short* hB  = (unsigned short*)alloc((size_t)(N_NODES + 1) * D * 2);
    unsigned short* WT  = (unsigned short*)alloc((size_t)3 * 128 * 256 * 2);
    int* rp_pad     = (int*)alloc((size_t)(N_NODES + 1) * 4);
    int* counts     = (int*)alloc((size_t)N_NODES * 4);
    int* cursor     = (int*)alloc((size_t)N_NODES * 4);
    int* src_pad    = (int*)alloc((size_t)(N_EDGES + 8 * N_NODES) * 4);
    int* bounds     = (int*)alloc((size_t)(N_GRAPHS + 1) * 4);
    int* local_pre  = (int*)alloc((size_t)N_NODES * 4);
    int* blocksums  = (int*)alloc((size_t)SCAN_NBLK * 4);

    // zero the dummy rows + counts
    hipMemsetAsync(counts, 0, (size_t)N_NODES * 4, stream);
    hipMemsetAsync(xb + (size_t)N_NODES * D, 0, D * 2, stream);
    hipMemsetAsync(hA + (size_t)N_NODES * D, 0, D * 2, stream);
    hipMemsetAsync(hB + (size_t)N_NODES * D, 0, D * 2, stream);

    // CSR build (padded segments; reused for all 3 layers)
    k_hist<<<(N_EDGES + 255) / 256, 256, 0, stream>>>(ei, counts);
    k_scan1<<<SCAN_NBLK, 256, 0, stream>>>(counts, local_pre, blocksums);
    k_scan2<<<1, 256, 0, stream>>>(blocksums);
    k_scan3<<<SCAN_NBLK, 256, 0, stream>>>(local_pre, blocksums, counts, rp_pad, cursor);
    k_scatter<<<(N_EDGES + 255) / 256, 256, 0, stream>>>(ei, cursor, src_pad);
    k_pad<<<SCAN_NBLK, 256, 0, stream>>>(cursor, rp_pad, src_pad);
    k_bounds<<<(N_NODES + 255) / 256, 256, 0, stream>>>(batch, bounds);

    // dtype prep
    k_x2b<<<(N_NODES * D / 8 + 255) / 256, 256, 0, stream>>>(x, (unsigned int*)xb);
    k_wprep3<<<384, 256, 0, stream>>>(Wrel[0], Wroot[0], Wrel[1], Wroot[1],
                                      Wrel[2], Wroot[2], WT);

    // 3 fused GraphConv layers
    const unsigned short* in = xb;
    unsigned short* houts[3] = {hA, hB, hA};
    for (int l = 0; l < 3; ++l) {
        k_layer<<<N_NODES / 16, 256, 0, stream>>>(in, rp_pad, src_pad,
                                                  WT + (size_t)l * 128 * 256,
                                                  brel[l], houts[l], (l < 2) ? 1 : 0);
        in = houts[l];
    }

    // global max pool
    k_segmax<<<N_GRAPHS, 512, 0, stream>>>(houts[2], bounds, out);
}

// Round 6
// 281.610 us; speedup vs baseline: 1.9896x; 1.0495x over previous
//
#include <hip/hip_runtime.h>
#include <hip/hip_bf16.h>
#include <math.h>

#define N_NODES 40000
#define N_EDGES 640000
#define D 128
#define N_GRAPHS 128
#define SCAN_NBLK ((N_NODES + 255) / 256)   // 157
#define LDS_STRIDE 68                        // words per agg row (pad vs 64 to spread banks)

typedef __attribute__((ext_vector_type(8))) short bf16x8;
typedef __attribute__((ext_vector_type(4))) float f32x4;
typedef __attribute__((ext_vector_type(4))) unsigned int u32x4;

static __device__ __forceinline__ unsigned short f2b(float f) {
    unsigned int u = __float_as_uint(f);
    unsigned int r = (u + 0x7fffu + ((u >> 16) & 1u)) >> 16;  // RNE
    return (unsigned short)r;
}
static __device__ __forceinline__ float blo(unsigned int u) {
    return __uint_as_float(u << 16);
}
static __device__ __forceinline__ float bhi(unsigned int u) {
    return __uint_as_float(u & 0xffff0000u);
}

// ---- init: zero counts + dummy rows, compute graph bounds ------------------
__global__ void __launch_bounds__(256) k_init(
    const int* __restrict__ batch, int* __restrict__ counts,
    int* __restrict__ bounds,
    unsigned short* __restrict__ xb, unsigned short* __restrict__ hA,
    unsigned short* __restrict__ hB) {
    int n = blockIdx.x * 256 + threadIdx.x;
    if (n < N_NODES) {
        counts[n] = 0;
        int b = batch[n];
        if (n == 0) {
            for (int g = 0; g <= b; ++g) bounds[g] = 0;
        } else {
            int pb = batch[n - 1];
            for (int g = pb + 1; g <= b; ++g) bounds[g] = n;
        }
        if (n == N_NODES - 1) {
            for (int g = b + 1; g <= N_GRAPHS; ++g) bounds[g] = N_NODES;
        }
    }
    if (blockIdx.x == SCAN_NBLK) {   // block 157: zero the 3 dummy rows
        int t = threadIdx.x;
        if (t < 48) {
            int row = t >> 4, c = t & 15;
            unsigned short* p = (row == 0) ? xb : (row == 1) ? hA : hB;
            u32x4 z = {0u, 0u, 0u, 0u};
            ((u32x4*)(p + (size_t)N_NODES * D))[c] = z;
        }
    }
}

// ---- packed: hist (2500 blk) + x2b (2500 blk) + wprep3 (384 blk) -----------
__global__ void __launch_bounds__(256) k_pack1(
    const int* __restrict__ ei, int* __restrict__ counts,
    const float* __restrict__ x, unsigned int* __restrict__ xb,
    const float* __restrict__ Wr0, const float* __restrict__ Wt0,
    const float* __restrict__ Wr1, const float* __restrict__ Wt1,
    const float* __restrict__ Wr2, const float* __restrict__ Wt2,
    unsigned short* __restrict__ WT) {
    int b = blockIdx.x;
    int t = threadIdx.x;
    if (b < 2500) {
        // hist: exactly 640000 edges
        int e = b * 256 + t;
        atomicAdd(&counts[ei[N_EDGES + e]], 1);
    } else if (b < 5000) {
        // x2b: 8 floats -> 4 packed bf16-pair uints; exactly 640000 groups
        int i = (b - 2500) * 256 + t;
        const f32x4* xv = (const f32x4*)x;
        f32x4 v0 = xv[i * 2], v1 = xv[i * 2 + 1];
        u32x4 o;
        o.x = ((unsigned int)f2b(v0.y) << 16) | f2b(v0.x);
        o.y = ((unsigned int)f2b(v0.w) << 16) | f2b(v0.z);
        o.z = ((unsigned int)f2b(v1.y) << 16) | f2b(v1.x);
        o.w = ((unsigned int)f2b(v1.w) << 16) | f2b(v1.z);
        ((u32x4*)xb)[i] = o;
    } else {
        // wprep3: WT[l][c][k], k<128 -> W_rel[k][c], else W_root[k-128][c]
        int bw = b - 5000;                 // 0..383
        int l = bw >> 7, c = bw & 127, k = t;
        const float* Wrel = (l == 0) ? Wr0 : (l == 1) ? Wr1 : Wr2;
        const float* Wroot = (l == 0) ? Wt0 : (l == 1) ? Wt1 : Wt2;
        float v = (k < D) ? Wrel[k * D + c] : Wroot[(k - D) * D + c];
        WT[(size_t)l * 128 * 256 + c * 256 + k] = f2b(v);
    }
}

// ---- 3-phase exclusive scan of padded (x16) degrees ------------------------
__global__ void __launch_bounds__(256) k_scan1(const int* __restrict__ counts,
                                               int* __restrict__ local_pre,
                                               int* __restrict__ blocksums) {
    int t = threadIdx.x;
    int i = blockIdx.x * 256 + t;
    int lane = t & 63, wave = t >> 6;
    int v = (i < N_NODES) ? ((counts[i] + 15) & ~15) : 0;   // pad degree to x16
    int incl = v;
#pragma unroll
    for (int off = 1; off < 64; off <<= 1) {
        int u = __shfl_up(incl, off);
        if (lane >= off) incl += u;
    }
    __shared__ int ws[4];
    if (lane == 63) ws[wave] = incl;
    __syncthreads();
    int base = 0;
    for (int w = 0; w < 4; ++w) {
        int s = ws[w];
        if (w < wave) base += s;
    }
    if (i < N_NODES) local_pre[i] = base + incl - v;
    if (t == 255) blocksums[blockIdx.x] = base + incl;
}

__global__ void __launch_bounds__(256) k_scan2(int* __restrict__ blocksums) {
    int t = threadIdx.x;
    int lane = t & 63, wave = t >> 6;
    int v = (t < SCAN_NBLK) ? blocksums[t] : 0;
    int incl = v;
#pragma unroll
    for (int off = 1; off < 64; off <<= 1) {
        int u = __shfl_up(incl, off);
        if (lane >= off) incl += u;
    }
    __shared__ int ws[4];
    if (lane == 63) ws[wave] = incl;
    __syncthreads();
    int base = 0;
    for (int w = 0; w < 4; ++w) {
        int s = ws[w];
        if (w < wave) base += s;
    }
    if (t < SCAN_NBLK) blocksums[t] = base + incl - v;
}

// scan3 + dummy-slot fill: dummy range [rp+deg, rp+pad16(deg)) is known now.
__global__ void __launch_bounds__(256) k_scan3(const int* __restrict__ local_pre,
                                               const int* __restrict__ blocksums,
                                               const int* __restrict__ counts,
                                               int* __restrict__ rp_pad,
                                               int* __restrict__ cursor,
                                               int* __restrict__ src_pad) {
    int i = blockIdx.x * 256 + threadIdx.x;
    if (i < N_NODES) {
        int rp = blocksums[blockIdx.x] + local_pre[i];
        rp_pad[i] = rp;
        cursor[i] = rp;
        int c = counts[i];
        int pc = (c + 15) & ~15;
        for (int j = rp + c; j < rp + pc; ++j) src_pad[j] = N_NODES;
        if (i == N_NODES - 1) rp_pad[N_NODES] = rp + pc;
    }
}

__global__ void k_scatter(const int* __restrict__ ei, int* __restrict__ cursor,
                          int* __restrict__ src_pad) {
    int e = blockIdx.x * blockDim.x + threadIdx.x;
    if (e < N_EDGES) {
        int d = ei[N_EDGES + e];
        int pos = atomicAdd(&cursor[d], 1);
        src_pad[pos] = ei[e];
    }
}

// ---- fused layer: CSR gather-sum (to LDS) + MFMA GEMM ----------------------
// Block = 16 nodes, 4 waves. Lane = (q = node slot lane>>4, c = chunk lane&15).
// Phase 1: 4 nodes per wave in parallel; per trip each 16-lane group reads 16
//   full rows of its node (group-uniform indices -> contiguous 256B segments),
//   64 rows (16KB) in flight per wave. Segments padded to x16 with the zero
//   row N_NODES (L1-hot) -> ntrips mostly 1, no tail.
// Phase 2: GEMM out[16][128] = [aggLDS|X] @ [W_rel;W_root] + b.
__global__ void __launch_bounds__(256) k_layer(
    const unsigned short* __restrict__ in,  // [N+1][128] bf16 (row N zero)
    const int* __restrict__ rp_pad,
    const int* __restrict__ src_pad,
    const unsigned short* __restrict__ WT,  // [128][256] bf16 (k contiguous)
    const float* __restrict__ bias,
    unsigned short* __restrict__ out,       // [N+1][128] bf16
    int relu) {
    __shared__ unsigned int aggLDS[16 * LDS_STRIDE];
    int tid = threadIdx.x;
    int w = tid >> 6;
    int lane = tid & 63;
    int q = lane >> 4;      // node slot / MFMA quad
    int c = lane & 15;      // 16B chunk / MFMA row
    int nl = w * 4 + q;
    int nodebase = blockIdx.x * 16;
    const u32x4* inv = (const u32x4*)in;

    // ---- phase 1 ----
    int s = rp_pad[nodebase + nl];
    int e = rp_pad[nodebase + nl + 1];
    const int4* sidx = (const int4*)(src_pad + s);
    int ntrips = (e - s) >> 4;

    float a0 = 0.f, a1 = 0.f, a2 = 0.f, a3 = 0.f;
    float a4 = 0.f, a5 = 0.f, a6 = 0.f, a7 = 0.f;

#define ACC8(v) do { \
        a0 += blo((v).x); a1 += bhi((v).x); \
        a2 += blo((v).y); a3 += bhi((v).y); \
        a4 += blo((v).z); a5 += bhi((v).z); \
        a6 += blo((v).w); a7 += bhi((v).w); } while (0)

    for (int t = 0; t < ntrips; ++t) {
        int4 ia = sidx[4 * t + 0];
        int4 ib = sidx[4 * t + 1];
        int4 ic = sidx[4 * t + 2];
        int4 id = sidx[4 * t + 3];
        u32x4 v0 = inv[ia.x * 16 + c];
        u32x4 v1 = inv[ia.y * 16 + c];
        u32x4 v2 = inv[ia.z * 16 + c];
        u32x4 v3 = inv[ia.w * 16 + c];
        u32x4 v4 = inv[ib.x * 16 + c];
        u32x4 v5 = inv[ib.y * 16 + c];
        u32x4 v6 = inv[ib.z * 16 + c];
        u32x4 v7 = inv[ib.w * 16 + c];
        u32x4 v8 = inv[ic.x * 16 + c];
        u32x4 v9 = inv[ic.y * 16 + c];
        u32x4 va = inv[ic.z * 16 + c];
        u32x4 vb = inv[ic.w * 16 + c];
        u32x4 vc = inv[id.x * 16 + c];
        u32x4 vd = inv[id.y * 16 + c];
        u32x4 ve = inv[id.z * 16 + c];
        u32x4 vf = inv[id.w * 16 + c];
        ACC8(v0); ACC8(v1); ACC8(v2); ACC8(v3);
        ACC8(v4); ACC8(v5); ACC8(v6); ACC8(v7);
        ACC8(v8); ACC8(v9); ACC8(va); ACC8(vb);
        ACC8(vc); ACC8(vd); ACC8(ve); ACC8(vf);
    }
#undef ACC8

    u32x4 o;
    o.x = ((unsigned int)f2b(a1) << 16) | f2b(a0);
    o.y = ((unsigned int)f2b(a3) << 16) | f2b(a2);
    o.z = ((unsigned int)f2b(a5) << 16) | f2b(a4);
    o.w = ((unsigned int)f2b(a7) << 16) | f2b(a6);
    *(u32x4*)&aggLDS[nl * LDS_STRIDE + c * 4] = o;   // linear feats: word i = feats 2i,2i+1
    __syncthreads();

    // ---- phase 2: GEMM ----
    int row = c, quad = q;
    int colbase = w * 32;

    f32x4 acc0 = {0.f, 0.f, 0.f, 0.f};
    f32x4 acc1 = {0.f, 0.f, 0.f, 0.f};

    const unsigned int* Al = &aggLDS[row * LDS_STRIDE];
    const short* Xp = (const short*)(in + (nodebase + row) * D);
    const short* W0 = (const short*)(WT + (colbase + row) * 256);
    const short* W1 = (const short*)(WT + (colbase + 16 + row) * 256);

#pragma unroll
    for (int t = 0; t < 4; ++t) {
        bf16x8 af = *(const bf16x8*)(Al + t * 16 + quad * 4);
        int k0 = t * 32 + quad * 8;
        bf16x8 b0 = *(const bf16x8*)(W0 + k0);
        bf16x8 b1 = *(const bf16x8*)(W1 + k0);
        acc0 = __builtin_amdgcn_mfma_f32_16x16x32_bf16(af, b0, acc0, 0, 0, 0);
        acc1 = __builtin_amdgcn_mfma_f32_16x16x32_bf16(af, b1, acc1, 0, 0, 0);
    }
#pragma unroll
    for (int t = 0; t < 4; ++t) {
        int k0 = t * 32 + quad * 8;
        bf16x8 xf = *(const bf16x8*)(Xp + k0);
        bf16x8 b0 = *(const bf16x8*)(W0 + 128 + k0);
        bf16x8 b1 = *(const bf16x8*)(W1 + 128 + k0);
        acc0 = __builtin_amdgcn_mfma_f32_16x16x32_bf16(xf, b0, acc0, 0, 0, 0);
        acc1 = __builtin_amdgcn_mfma_f32_16x16x32_bf16(xf, b1, acc1, 0, 0, 0);
    }

    int c0 = colbase + row, c1 = c0 + 16;
    float bia0 = bias[c0], bia1 = bias[c1];
#pragma unroll
    for (int r = 0; r < 4; ++r) {
        int n2 = nodebase + quad * 4 + r;
        float v0 = acc0[r] + bia0;
        float v1 = acc1[r] + bia1;
        if (relu) { v0 = fmaxf(v0, 0.f); v1 = fmaxf(v1, 0.f); }
        out[n2 * D + c0] = f2b(v0);
        out[n2 * D + c1] = f2b(v1);
    }
}

// ---- segment_max over sorted batch ----------------------------------------
__global__ void __launch_bounds__(512) k_segmax(const unsigned short* __restrict__ h,
                                                const int* __restrict__ bounds,
                                                float* __restrict__ out) {
    __shared__ float sm[8][128];
    int g = blockIdx.x;
    int tid = threadIdx.x;
    int rg = tid >> 6;      // 0..7
    int c = tid & 63;       // uint col -> feats 2c, 2c+1
    int s = bounds[g], e = bounds[g + 1];
    const unsigned int* h32 = (const unsigned int*)h;

    float m0 = -INFINITY, m1 = -INFINITY;
    int n = s + rg;
    for (; n + 8 < e; n += 16) {
        unsigned int v0 = h32[n * 64 + c];
        unsigned int v1 = h32[(n + 8) * 64 + c];
        m0 = fmaxf(m0, blo(v0)); m1 = fmaxf(m1, bhi(v0));
        m0 = fmaxf(m0, blo(v1)); m1 = fmaxf(m1, bhi(v1));
    }
    if (n < e) {
        unsigned int v0 = h32[n * 64 + c];
        m0 = fmaxf(m0, blo(v0)); m1 = fmaxf(m1, bhi(v0));
    }
    sm[rg][c * 2] = m0;
    sm[rg][c * 2 + 1] = m1;
    __syncthreads();
    if (tid < 128) {
        float m = sm[0][tid];
#pragma unroll
        for (int r = 1; r < 8; ++r) m = fmaxf(m, sm[r][tid]);
        out[g * D + tid] = m;
    }
}

extern "C" void kernel_launch(void* const* d_in, const int* in_sizes, int n_in,
                              void* d_out, int out_size, void* d_ws, size_t ws_size,
                              hipStream_t stream) {
    const float* x = (const float*)d_in[0];
    const int* ei = (const int*)d_in[1];
    const int* batch = (const int*)d_in[2];
    const float* Wrel[3]  = {(const float*)d_in[3], (const float*)d_in[6], (const float*)d_in[9]};
    const float* brel[3]  = {(const float*)d_in[4], (const float*)d_in[7], (const float*)d_in[10]};
    const float* Wroot[3] = {(const float*)d_in[5], (const float*)d_in[8], (const float*)d_in[11]};
    float* out = (float*)d_out;

    char* ws = (char*)d_ws;
    size_t off = 0;
    auto alloc = [&](size_t bytes) -> void* {
        void* p = ws + off;
        off = (off + bytes + 255) & ~(size_t)255;
        return p;
    };
    // activation buffers have one extra zero row (index N_NODES)
    unsigned short* xb  = (unsigned short*)alloc((size_t)(N_NODES + 1) * D * 2);
    unsigned short* hA  = (unsigned short*)alloc((size_t)(N_NODES + 1) * D * 2);
    unsigned short* hB  = (unsigned short*)alloc((size_t)(N_NODES + 1) * D * 2);
    unsigned short* WT  = (unsigned short*)alloc((size_t)3 * 128 * 256 * 2);
    int* rp_pad     = (int*)alloc((size_t)(N_NODES + 1) * 4);
    int* counts     = (int*)alloc((size_t)N_NODES * 4);
    int* cursor     = (int*)alloc((size_t)N_NODES * 4);
    int* src_pad    = (int*)alloc((size_t)(N_EDGES + 16 * N_NODES) * 4);
    int* bounds     = (int*)alloc((size_t)(N_GRAPHS + 1) * 4);
    int* local_pre  = (int*)alloc((size_t)N_NODES * 4);
    int* blocksums  = (int*)alloc((size_t)SCAN_NBLK * 4);

    // init (zero counts + dummy rows) + bounds
    k_init<<<SCAN_NBLK + 1, 256, 0, stream>>>(batch, counts, bounds, xb, hA, hB);
    // packed: hist + x2b + wprep3
    k_pack1<<<5384, 256, 0, stream>>>(ei, counts, x, (unsigned int*)xb,
                                      Wrel[0], Wroot[0], Wrel[1], Wroot[1],
                                      Wrel[2], Wroot[2], WT);
    // scan (padded degrees) + dummy fill + scatter
    k_scan1<<<SCAN_NBLK, 256, 0, stream>>>(counts, local_pre, blocksums);
    k_scan2<<<1, 256, 0, stream>>>(blocksums);
    k_scan3<<<SCAN_NBLK, 256, 0, stream>>>(local_pre, blocksums, counts,
                                           rp_pad, cursor, src_pad);
    k_scatter<<<(N_EDGES + 255) / 256, 256, 0, stream>>>(ei, cursor, src_pad);

    // 3 fused GraphConv layers
    const unsigned short* in = xb;
    unsigned short* houts[3] = {hA, hB, hA};
    for (int l = 0; l < 3; ++l) {
        k_layer<<<N_NODES / 16, 256, 0, stream>>>(in, rp_pad, src_pad,
                                                  WT + (size_t)l * 128 * 256,
                                                  brel[l], houts[l], (l < 2) ? 1 : 0);
        in = houts[l];
    }

    // global max pool
    k_segmax<<<N_GRAPHS, 512, 0, stream>>>(houts[2], bounds, out);
}

// Round 7
// 276.115 us; speedup vs baseline: 2.0292x; 1.0199x over previous
//
#include <hip/hip_runtime.h>
#include <hip/hip_bf16.h>
#include <math.h>

#define N_NODES 40000
#define N_EDGES 640000
#define D 128
#define N_GRAPHS 128
#define SCAN_NBLK ((N_NODES + 255) / 256)   // 157
#define LDS_STRIDE 68                        // words per agg row (pad vs 64 to spread banks)

typedef __attribute__((ext_vector_type(8))) short bf16x8;
typedef __attribute__((ext_vector_type(4))) float f32x4;
typedef __attribute__((ext_vector_type(4))) unsigned int u32x4;

static __device__ __forceinline__ unsigned short f2b(float f) {
    unsigned int u = __float_as_uint(f);
    unsigned int r = (u + 0x7fffu + ((u >> 16) & 1u)) >> 16;  // RNE
    return (unsigned short)r;
}
static __device__ __forceinline__ float blo(unsigned int u) {
    return __uint_as_float(u << 16);
}
static __device__ __forceinline__ float bhi(unsigned int u) {
    return __uint_as_float(u & 0xffff0000u);
}
// monotonic f32 -> u32 key (unsigned order == float order)
static __device__ __forceinline__ unsigned int fkey(float x) {
    unsigned int b = __float_as_uint(x);
    return (b & 0x80000000u) ? ~b : (b | 0x80000000u);
}

// ---- init: zero counts + dummy rows, graph bounds, seed out keys -----------
__global__ void __launch_bounds__(256) k_init(
    const int* __restrict__ batch, int* __restrict__ counts,
    int* __restrict__ bounds,
    unsigned short* __restrict__ xb, unsigned short* __restrict__ hA,
    unsigned short* __restrict__ hB, unsigned int* __restrict__ outk) {
    int n = blockIdx.x * 256 + threadIdx.x;
    if (n < N_GRAPHS * D) outk[n] = 0x007FFFFFu;   // key(-inf)
    if (n < N_NODES) {
        counts[n] = 0;
        int b = batch[n];
        if (n == 0) {
            for (int g = 0; g <= b; ++g) bounds[g] = 0;
        } else {
            int pb = batch[n - 1];
            for (int g = pb + 1; g <= b; ++g) bounds[g] = n;
        }
        if (n == N_NODES - 1) {
            for (int g = b + 1; g <= N_GRAPHS; ++g) bounds[g] = N_NODES;
        }
    }
    if (blockIdx.x == SCAN_NBLK) {   // block 157: zero the 3 dummy rows
        int t = threadIdx.x;
        if (t < 48) {
            int row = t >> 4, c = t & 15;
            unsigned short* p = (row == 0) ? xb : (row == 1) ? hA : hB;
            u32x4 z = {0u, 0u, 0u, 0u};
            ((u32x4*)(p + (size_t)N_NODES * D))[c] = z;
        }
    }
}

// ---- packed: hist (2500 blk) + x2b (2500 blk) + wprep3 (384 blk) -----------
__global__ void __launch_bounds__(256) k_pack1(
    const int* __restrict__ ei, int* __restrict__ counts,
    const float* __restrict__ x, unsigned int* __restrict__ xb,
    const float* __restrict__ Wr0, const float* __restrict__ Wt0,
    const float* __restrict__ Wr1, const float* __restrict__ Wt1,
    const float* __restrict__ Wr2, const float* __restrict__ Wt2,
    unsigned short* __restrict__ WT) {
    int b = blockIdx.x;
    int t = threadIdx.x;
    if (b < 2500) {
        int e = b * 256 + t;
        atomicAdd(&counts[ei[N_EDGES + e]], 1);
    } else if (b < 5000) {
        int i = (b - 2500) * 256 + t;
        const f32x4* xv = (const f32x4*)x;
        f32x4 v0 = xv[i * 2], v1 = xv[i * 2 + 1];
        u32x4 o;
        o.x = ((unsigned int)f2b(v0.y) << 16) | f2b(v0.x);
        o.y = ((unsigned int)f2b(v0.w) << 16) | f2b(v0.z);
        o.z = ((unsigned int)f2b(v1.y) << 16) | f2b(v1.x);
        o.w = ((unsigned int)f2b(v1.w) << 16) | f2b(v1.z);
        ((u32x4*)xb)[i] = o;
    } else {
        int bw = b - 5000;                 // 0..383
        int l = bw >> 7, c = bw & 127, k = t;
        const float* Wrel = (l == 0) ? Wr0 : (l == 1) ? Wr1 : Wr2;
        const float* Wroot = (l == 0) ? Wt0 : (l == 1) ? Wt1 : Wt2;
        float v = (k < D) ? Wrel[k * D + c] : Wroot[(k - D) * D + c];
        WT[(size_t)l * 128 * 256 + c * 256 + k] = f2b(v);
    }
}

// ---- 3-phase exclusive scan of padded (x16) degrees ------------------------
__global__ void __launch_bounds__(256) k_scan1(const int* __restrict__ counts,
                                               int* __restrict__ local_pre,
                                               int* __restrict__ blocksums) {
    int t = threadIdx.x;
    int i = blockIdx.x * 256 + t;
    int lane = t & 63, wave = t >> 6;
    int v = (i < N_NODES) ? ((counts[i] + 15) & ~15) : 0;   // pad degree to x16
    int incl = v;
#pragma unroll
    for (int off = 1; off < 64; off <<= 1) {
        int u = __shfl_up(incl, off);
        if (lane >= off) incl += u;
    }
    __shared__ int ws[4];
    if (lane == 63) ws[wave] = incl;
    __syncthreads();
    int base = 0;
    for (int w = 0; w < 4; ++w) {
        int s = ws[w];
        if (w < wave) base += s;
    }
    if (i < N_NODES) local_pre[i] = base + incl - v;
    if (t == 255) blocksums[blockIdx.x] = base + incl;
}

__global__ void __launch_bounds__(256) k_scan2(int* __restrict__ blocksums) {
    int t = threadIdx.x;
    int lane = t & 63, wave = t >> 6;
    int v = (t < SCAN_NBLK) ? blocksums[t] : 0;
    int incl = v;
#pragma unroll
    for (int off = 1; off < 64; off <<= 1) {
        int u = __shfl_up(incl, off);
        if (lane >= off) incl += u;
    }
    __shared__ int ws[4];
    if (lane == 63) ws[wave] = incl;
    __syncthreads();
    int base = 0;
    for (int w = 0; w < 4; ++w) {
        int s = ws[w];
        if (w < wave) base += s;
    }
    if (t < SCAN_NBLK) blocksums[t] = base + incl - v;
}

__global__ void __launch_bounds__(256) k_scan3(const int* __restrict__ local_pre,
                                               const int* __restrict__ blocksums,
                                               const int* __restrict__ counts,
                                               int* __restrict__ rp_pad,
                                               int* __restrict__ cursor,
                                               int* __restrict__ src_pad) {
    int i = blockIdx.x * 256 + threadIdx.x;
    if (i < N_NODES) {
        int rp = blocksums[blockIdx.x] + local_pre[i];
        rp_pad[i] = rp;
        cursor[i] = rp;
        int c = counts[i];
        int pc = (c + 15) & ~15;
        for (int j = rp + c; j < rp + pc; ++j) src_pad[j] = N_NODES;
        if (i == N_NODES - 1) rp_pad[N_NODES] = rp + pc;
    }
}

__global__ void k_scatter(const int* __restrict__ ei, int* __restrict__ cursor,
                          int* __restrict__ src_pad) {
    int e = blockIdx.x * blockDim.x + threadIdx.x;
    if (e < N_EDGES) {
        int d = ei[N_EDGES + e];
        int pos = atomicAdd(&cursor[d], 1);
        src_pad[pos] = ei[e];
    }
}

// ---- fused layer: CSR gather-sum (LDS) + MFMA GEMM (+ fused max-pool) ------
// Block = 16 nodes, 4 waves. Lane = (q = node slot lane>>4, c = chunk lane&15).
// Phase 1: 4 nodes per wave in parallel; 16 group-uniform full-row reads per
//   trip (contiguous 256B segments). Segments padded to x16 with zero row.
// Phase 2: GEMM out[16][128] = [aggLDS|X] @ [W_rel;W_root] + b. X-frags and
//   agg-half W-frags are loaded BEFORE phase 1 to overlap latency.
// Epilogue: outk==null -> relu+store bf16; else fold global_max_pool:
//   block-wide column max (reg + 2 shfl hops) + one atomicMax(key) per col.
__global__ void __launch_bounds__(256) k_layer(
    const unsigned short* __restrict__ in,  // [N+1][128] bf16 (row N zero)
    const int* __restrict__ rp_pad,
    const int* __restrict__ src_pad,
    const unsigned short* __restrict__ WT,  // [128][256] bf16 (k contiguous)
    const float* __restrict__ bias,
    unsigned short* __restrict__ out,       // [N+1][128] bf16 (unused if outk)
    const int* __restrict__ batch,
    unsigned int* __restrict__ outk) {      // null for layers 0,1
    __shared__ unsigned int aggLDS[16 * LDS_STRIDE];
    int tid = threadIdx.x;
    int w = tid >> 6;
    int lane = tid & 63;
    int q = lane >> 4;      // node slot / MFMA quad
    int c = lane & 15;      // 16B chunk / MFMA row
    int nl = w * 4 + q;
    int nodebase = blockIdx.x * 16;
    const u32x4* inv = (const u32x4*)in;

    // ---- hoisted phase-2 loads (independent of the gather) ----
    int row = c, quad = q;
    int colbase = w * 32;
    const short* Xp = (const short*)(in + (nodebase + row) * D);
    const short* W0 = (const short*)(WT + (colbase + row) * 256);
    const short* W1 = (const short*)(WT + (colbase + 16 + row) * 256);
    bf16x8 xf[4], b0a[4], b1a[4];
#pragma unroll
    for (int t = 0; t < 4; ++t) {
        int k0 = t * 32 + quad * 8;
        xf[t] = *(const bf16x8*)(Xp + k0);
        b0a[t] = *(const bf16x8*)(W0 + k0);
        b1a[t] = *(const bf16x8*)(W1 + k0);
    }

    // ---- phase 1: gather-sum ----
    int s = rp_pad[nodebase + nl];
    int e = rp_pad[nodebase + nl + 1];
    const int4* sidx = (const int4*)(src_pad + s);
    int ntrips = (e - s) >> 4;

    float a0 = 0.f, a1 = 0.f, a2 = 0.f, a3 = 0.f;
    float a4 = 0.f, a5 = 0.f, a6 = 0.f, a7 = 0.f;

#define ACC8(v) do { \
        a0 += blo((v).x); a1 += bhi((v).x); \
        a2 += blo((v).y); a3 += bhi((v).y); \
        a4 += blo((v).z); a5 += bhi((v).z); \
        a6 += blo((v).w); a7 += bhi((v).w); } while (0)

    for (int t = 0; t < ntrips; ++t) {
        int4 ia = sidx[4 * t + 0];
        int4 ib = sidx[4 * t + 1];
        int4 ic = sidx[4 * t + 2];
        int4 id = sidx[4 * t + 3];
        u32x4 v0 = inv[ia.x * 16 + c];
        u32x4 v1 = inv[ia.y * 16 + c];
        u32x4 v2 = inv[ia.z * 16 + c];
        u32x4 v3 = inv[ia.w * 16 + c];
        u32x4 v4 = inv[ib.x * 16 + c];
        u32x4 v5 = inv[ib.y * 16 + c];
        u32x4 v6 = inv[ib.z * 16 + c];
        u32x4 v7 = inv[ib.w * 16 + c];
        u32x4 v8 = inv[ic.x * 16 + c];
        u32x4 v9 = inv[ic.y * 16 + c];
        u32x4 va = inv[ic.z * 16 + c];
        u32x4 vb = inv[ic.w * 16 + c];
        u32x4 vc = inv[id.x * 16 + c];
        u32x4 vd = inv[id.y * 16 + c];
        u32x4 ve = inv[id.z * 16 + c];
        u32x4 vf = inv[id.w * 16 + c];
        ACC8(v0); ACC8(v1); ACC8(v2); ACC8(v3);
        ACC8(v4); ACC8(v5); ACC8(v6); ACC8(v7);
        ACC8(v8); ACC8(v9); ACC8(va); ACC8(vb);
        ACC8(vc); ACC8(vd); ACC8(ve); ACC8(vf);
    }
#undef ACC8

    u32x4 o;
    o.x = ((unsigned int)f2b(a1) << 16) | f2b(a0);
    o.y = ((unsigned int)f2b(a3) << 16) | f2b(a2);
    o.z = ((unsigned int)f2b(a5) << 16) | f2b(a4);
    o.w = ((unsigned int)f2b(a7) << 16) | f2b(a6);
    *(u32x4*)&aggLDS[nl * LDS_STRIDE + c * 4] = o;   // linear feats: word i = feats 2i,2i+1
    __syncthreads();

    // ---- phase 2: GEMM ----
    f32x4 acc0 = {0.f, 0.f, 0.f, 0.f};
    f32x4 acc1 = {0.f, 0.f, 0.f, 0.f};
    const unsigned int* Al = &aggLDS[row * LDS_STRIDE];

#pragma unroll
    for (int t = 0; t < 4; ++t) {
        bf16x8 af = *(const bf16x8*)(Al + t * 16 + quad * 4);
        acc0 = __builtin_amdgcn_mfma_f32_16x16x32_bf16(af, b0a[t], acc0, 0, 0, 0);
        acc1 = __builtin_amdgcn_mfma_f32_16x16x32_bf16(af, b1a[t], acc1, 0, 0, 0);
    }
#pragma unroll
    for (int t = 0; t < 4; ++t) {
        int k0 = t * 32 + quad * 8;
        bf16x8 b0 = *(const bf16x8*)(W0 + 128 + k0);
        bf16x8 b1 = *(const bf16x8*)(W1 + 128 + k0);
        acc0 = __builtin_amdgcn_mfma_f32_16x16x32_bf16(xf[t], b0, acc0, 0, 0, 0);
        acc1 = __builtin_amdgcn_mfma_f32_16x16x32_bf16(xf[t], b1, acc1, 0, 0, 0);
    }

    int c0 = colbase + row, c1 = c0 + 16;
    float bia0 = bias[c0], bia1 = bias[c1];
    float v0[4], v1[4];
#pragma unroll
    for (int r = 0; r < 4; ++r) { v0[r] = acc0[r] + bia0; v1[r] = acc1[r] + bia1; }

    if (outk == nullptr) {
        // layers 0,1: relu + bf16 store
#pragma unroll
        for (int r = 0; r < 4; ++r) {
            int n2 = nodebase + quad * 4 + r;
            out[n2 * D + c0] = f2b(fmaxf(v0[r], 0.f));
            out[n2 * D + c1] = f2b(fmaxf(v1[r], 0.f));
        }
    } else {
        // layer 2: fused global_max_pool (batch sorted)
        int g0 = batch[nodebase];
        int g15 = batch[nodebase + 15];
        if (g0 == g15) {
            float m0 = fmaxf(fmaxf(v0[0], v0[1]), fmaxf(v0[2], v0[3]));
            float m1 = fmaxf(fmaxf(v1[0], v1[1]), fmaxf(v1[2], v1[3]));
            m0 = fmaxf(m0, __shfl_xor(m0, 16)); m0 = fmaxf(m0, __shfl_xor(m0, 32));
            m1 = fmaxf(m1, __shfl_xor(m1, 16)); m1 = fmaxf(m1, __shfl_xor(m1, 32));
            if (quad == 0) {
                atomicMax(&outk[g0 * D + c0], fkey(m0));
                atomicMax(&outk[g0 * D + c1], fkey(m1));
            }
        } else {  // boundary block (~5%): per-value atomics
#pragma unroll
            for (int r = 0; r < 4; ++r) {
                int gg = batch[nodebase + quad * 4 + r];
                atomicMax(&outk[gg * D + c0], fkey(v0[r]));
                atomicMax(&outk[gg * D + c1], fkey(v1[r]));
            }
        }
    }
}

// ---- unmap keys -> floats (in place over d_out) ----------------------------
__global__ void k_unmap(unsigned int* __restrict__ outk) {
    int i = blockIdx.x * 256 + threadIdx.x;   // 64 blocks x 256 = 16384
    unsigned int k = outk[i];
    unsigned int b = (k & 0x80000000u) ? (k ^ 0x80000000u) : ~k;
    ((float*)outk)[i] = __uint_as_float(b);
}

extern "C" void kernel_launch(void* const* d_in, const int* in_sizes, int n_in,
                              void* d_out, int out_size, void* d_ws, size_t ws_size,
                              hipStream_t stream) {
    const float* x = (const float*)d_in[0];
    const int* ei = (const int*)d_in[1];
    const int* batch = (const int*)d_in[2];
    const float* Wrel[3]  = {(const float*)d_in[3], (const float*)d_in[6], (const float*)d_in[9]};
    const float* brel[3]  = {(const float*)d_in[4], (const float*)d_in[7], (const float*)d_in[10]};
    const float* Wroot[3] = {(const float*)d_in[5], (const float*)d_in[8], (const float*)d_in[11]};
    unsigned int* outk = (unsigned int*)d_out;

    char* ws = (char*)d_ws;
    size_t off = 0;
    auto alloc = [&](size_t bytes) -> void* {
        void* p = ws + off;
        off = (off + bytes + 255) & ~(size_t)255;
        return p;
    };
    // activation buffers have one extra zero row (index N_NODES)
    unsigned short* xb  = (unsigned short*)alloc((size_t)(N_NODES + 1) * D * 2);
    unsigned short* hA  = (unsigned short*)alloc((size_t)(N_NODES + 1) * D * 2);
    unsigned short* hB  = (unsigned short*)alloc((size_t)(N_NODES + 1) * D * 2);
    unsigned short* WT  = (unsigned short*)alloc((size_t)3 * 128 * 256 * 2);
    int* rp_pad     = (int*)alloc((size_t)(N_NODES + 1) * 4);
    int* counts     = (int*)alloc((size_t)N_NODES * 4);
    int* cursor     = (int*)alloc((size_t)N_NODES * 4);
    int* src_pad    = (int*)alloc((size_t)(N_EDGES + 16 * N_NODES) * 4);
    int* bounds     = (int*)alloc((size_t)(N_GRAPHS + 1) * 4);
    int* local_pre  = (int*)alloc((size_t)N_NODES * 4);
    int* blocksums  = (int*)alloc((size_t)SCAN_NBLK * 4);

    // init (zero counts + dummy rows + out keys) + bounds
    k_init<<<SCAN_NBLK + 1, 256, 0, stream>>>(batch, counts, bounds, xb, hA, hB, outk);
    // packed: hist + x2b + wprep3
    k_pack1<<<5384, 256, 0, stream>>>(ei, counts, x, (unsigned int*)xb,
                                      Wrel[0], Wroot[0], Wrel[1], Wroot[1],
                                      Wrel[2], Wroot[2], WT);
    // scan (padded degrees) + dummy fill + scatter
    k_scan1<<<SCAN_NBLK, 256, 0, stream>>>(counts, local_pre, blocksums);
    k_scan2<<<1, 256, 0, stream>>>(blocksums);
    k_scan3<<<SCAN_NBLK, 256, 0, stream>>>(local_pre, blocksums, counts,
                                           rp_pad, cursor, src_pad);
    k_scatter<<<(N_EDGES + 255) / 256, 256, 0, stream>>>(ei, cursor, src_pad);

    // 3 fused GraphConv layers; layer 2 folds the global max pool
    k_layer<<<N_NODES / 16, 256, 0, stream>>>(xb, rp_pad, src_pad, WT,
                                              brel[0], hA, batch, nullptr);
    k_layer<<<N_NODES / 16, 256, 0, stream>>>(hA, rp_pad, src_pad, WT + 128 * 256,
                                              brel[1], hB, batch, nullptr);
    k_layer<<<N_NODES / 16, 256, 0, stream>>>(hB, rp_pad, src_pad, WT + 2 * 128 * 256,
                                              brel[2], hB, batch, outk);

    // keys -> floats
    k_unmap<<<N_GRAPHS * D / 256, 256, 0, stream>>>(outk);
}

// Round 8
// 273.376 us; speedup vs baseline: 2.0496x; 1.0100x over previous
//
#include <hip/hip_runtime.h>
#include <hip/hip_bf16.h>
#include <math.h>

#define N_NODES 40000
#define N_EDGES 640000
#define D 128
#define N_GRAPHS 128
#define SCAN_NBLK ((N_NODES + 255) / 256)   // 157
#define LDS_STRIDE 68                        // words per agg row (pad vs 64 to spread banks)

typedef __attribute__((ext_vector_type(8))) short bf16x8;
typedef __attribute__((ext_vector_type(4))) float f32x4;
typedef __attribute__((ext_vector_type(4))) unsigned int u32x4;

static __device__ __forceinline__ unsigned short f2b(float f) {
    unsigned int u = __float_as_uint(f);
    unsigned int r = (u + 0x7fffu + ((u >> 16) & 1u)) >> 16;  // RNE
    return (unsigned short)r;
}
static __device__ __forceinline__ float blo(unsigned int u) {
    return __uint_as_float(u << 16);
}
static __device__ __forceinline__ float bhi(unsigned int u) {
    return __uint_as_float(u & 0xffff0000u);
}
// monotonic f32 -> u32 key (unsigned order == float order)
static __device__ __forceinline__ unsigned int fkey(float x) {
    unsigned int b = __float_as_uint(x);
    return (b & 0x80000000u) ? ~b : (b | 0x80000000u);
}

// ---- init: zero counts + dummy rows, graph bounds, seed out keys -----------
__global__ void __launch_bounds__(256) k_init(
    const int* __restrict__ batch, int* __restrict__ counts,
    unsigned short* __restrict__ xb, unsigned short* __restrict__ hA,
    unsigned short* __restrict__ hB, unsigned int* __restrict__ outk) {
    int n = blockIdx.x * 256 + threadIdx.x;
    if (n < N_GRAPHS * D) outk[n] = 0x007FFFFFu;   // key(-inf)
    if (n < N_NODES) counts[n] = 0;
    if (blockIdx.x == SCAN_NBLK) {   // block 157: zero the 3 dummy rows
        int t = threadIdx.x;
        if (t < 48) {
            int row = t >> 4, c = t & 15;
            unsigned short* p = (row == 0) ? xb : (row == 1) ? hA : hB;
            u32x4 z = {0u, 0u, 0u, 0u};
            ((u32x4*)(p + (size_t)N_NODES * D))[c] = z;
        }
    }
}

// ---- packed: hist (2500 blk) + x2b (2500 blk) + wprep3 (384 blk) -----------
__global__ void __launch_bounds__(256) k_pack1(
    const int* __restrict__ ei, int* __restrict__ counts,
    const float* __restrict__ x, unsigned int* __restrict__ xb,
    const float* __restrict__ Wr0, const float* __restrict__ Wt0,
    const float* __restrict__ Wr1, const float* __restrict__ Wt1,
    const float* __restrict__ Wr2, const float* __restrict__ Wt2,
    unsigned short* __restrict__ WT) {
    int b = blockIdx.x;
    int t = threadIdx.x;
    if (b < 2500) {
        int e = b * 256 + t;
        atomicAdd(&counts[ei[N_EDGES + e]], 1);
    } else if (b < 5000) {
        int i = (b - 2500) * 256 + t;
        const f32x4* xv = (const f32x4*)x;
        f32x4 v0 = xv[i * 2], v1 = xv[i * 2 + 1];
        u32x4 o;
        o.x = ((unsigned int)f2b(v0.y) << 16) | f2b(v0.x);
        o.y = ((unsigned int)f2b(v0.w) << 16) | f2b(v0.z);
        o.z = ((unsigned int)f2b(v1.y) << 16) | f2b(v1.x);
        o.w = ((unsigned int)f2b(v1.w) << 16) | f2b(v1.z);
        ((u32x4*)xb)[i] = o;
    } else {
        int bw = b - 5000;                 // 0..383
        int l = bw >> 7, c = bw & 127, k = t;
        const float* Wrel = (l == 0) ? Wr0 : (l == 1) ? Wr1 : Wr2;
        const float* Wroot = (l == 0) ? Wt0 : (l == 1) ? Wt1 : Wt2;
        float v = (k < D) ? Wrel[k * D + c] : Wroot[(k - D) * D + c];
        WT[(size_t)l * 128 * 256 + c * 256 + k] = f2b(v);
    }
}

// ---- scan of padded (x16) degrees ------------------------------------------
// Phase 1: per-block scan -> local exclusive prefix + block sum.
__global__ void __launch_bounds__(256) k_scan1(const int* __restrict__ counts,
                                               int* __restrict__ local_pre,
                                               int* __restrict__ blocksums) {
    int t = threadIdx.x;
    int i = blockIdx.x * 256 + t;
    int lane = t & 63, wave = t >> 6;
    int v = (i < N_NODES) ? ((counts[i] + 15) & ~15) : 0;   // pad degree to x16
    int incl = v;
#pragma unroll
    for (int off = 1; off < 64; off <<= 1) {
        int u = __shfl_up(incl, off);
        if (lane >= off) incl += u;
    }
    __shared__ int ws[4];
    if (lane == 63) ws[wave] = incl;
    __syncthreads();
    int base = 0;
    for (int w = 0; w < 4; ++w) {
        int s = ws[w];
        if (w < wave) base += s;
    }
    if (i < N_NODES) local_pre[i] = base + incl - v;
    if (t == 255) blocksums[blockIdx.x] = base + incl;
}

// Phase 2 (fused scan2+scan3): each block reduces blocksums[0..bid) itself,
// then emits row starts + cursor + dummy-slot fill.
__global__ void __launch_bounds__(256) k_scan3(const int* __restrict__ local_pre,
                                               const int* __restrict__ blocksums,
                                               const int* __restrict__ counts,
                                               int* __restrict__ rp_pad,
                                               int* __restrict__ cursor,
                                               int* __restrict__ src_pad) {
    int t = threadIdx.x;
    int lane = t & 63, wave = t >> 6;
    int bid = blockIdx.x;
    int v = (t < bid) ? blocksums[t] : 0;   // bid <= 156 < 256
#pragma unroll
    for (int off = 32; off >= 1; off >>= 1) v += __shfl_xor(v, off);
    __shared__ int ws[4];
    if (lane == 0) ws[wave] = v;
    __syncthreads();
    int base = ws[0] + ws[1] + ws[2] + ws[3];   // exclusive prefix for this block

    int i = bid * 256 + t;
    if (i < N_NODES) {
        int rp = base + local_pre[i];
        rp_pad[i] = rp;
        cursor[i] = rp;
        int c = counts[i];
        int pc = (c + 15) & ~15;
        for (int j = rp + c; j < rp + pc; ++j) src_pad[j] = N_NODES;
        if (i == N_NODES - 1) rp_pad[N_NODES] = rp + pc;
    }
}

__global__ void k_scatter(const int* __restrict__ ei, int* __restrict__ cursor,
                          int* __restrict__ src_pad) {
    int e = blockIdx.x * blockDim.x + threadIdx.x;
    if (e < N_EDGES) {
        int d = ei[N_EDGES + e];
        int pos = atomicAdd(&cursor[d], 1);
        src_pad[pos] = ei[e];
    }
}

// ---- fused layer: CSR gather-sum (LDS) + MFMA GEMM (+ fused max-pool) ------
// Block = 16 nodes, 4 waves. Lane = (q = node slot lane>>4, c = chunk lane&15).
// Phase 1: 4 nodes per wave in parallel; 16 group-uniform full-row reads per
//   trip (contiguous 256B segments). Segments padded to x16 with zero row.
// Phase 2: GEMM out[16][128] = [aggLDS|X] @ [W_rel;W_root] + b. All phase-2
//   loads issued AFTER the barrier: keeping VGPR<=64 (8 waves/SIMD) beats
//   hoisting for latency overlap (R7: 76 VGPR -> occupancy 25%, +4us/layer).
// Epilogue: outk==null -> relu+store bf16; else fold global_max_pool.
__global__ void __launch_bounds__(256) k_layer(
    const unsigned short* __restrict__ in,  // [N+1][128] bf16 (row N zero)
    const int* __restrict__ rp_pad,
    const int* __restrict__ src_pad,
    const unsigned short* __restrict__ WT,  // [128][256] bf16 (k contiguous)
    const float* __restrict__ bias,
    unsigned short* __restrict__ out,       // [N+1][128] bf16 (unused if outk)
    const int* __restrict__ batch,
    unsigned int* __restrict__ outk) {      // null for layers 0,1
    __shared__ unsigned int aggLDS[16 * LDS_STRIDE];
    int tid = threadIdx.x;
    int w = tid >> 6;
    int lane = tid & 63;
    int q = lane >> 4;      // node slot / MFMA quad
    int c = lane & 15;      // 16B chunk / MFMA row
    int nl = w * 4 + q;
    int nodebase = blockIdx.x * 16;
    const u32x4* inv = (const u32x4*)in;

    // ---- phase 1: gather-sum ----
    int s = rp_pad[nodebase + nl];
    int e = rp_pad[nodebase + nl + 1];
    const int4* sidx = (const int4*)(src_pad + s);
    int ntrips = (e - s) >> 4;

    float a0 = 0.f, a1 = 0.f, a2 = 0.f, a3 = 0.f;
    float a4 = 0.f, a5 = 0.f, a6 = 0.f, a7 = 0.f;

#define ACC8(v) do { \
        a0 += blo((v).x); a1 += bhi((v).x); \
        a2 += blo((v).y); a3 += bhi((v).y); \
        a4 += blo((v).z); a5 += bhi((v).z); \
        a6 += blo((v).w); a7 += bhi((v).w); } while (0)

    for (int t = 0; t < ntrips; ++t) {
        int4 ia = sidx[4 * t + 0];
        int4 ib = sidx[4 * t + 1];
        int4 ic = sidx[4 * t + 2];
        int4 id = sidx[4 * t + 3];
        u32x4 v0 = inv[ia.x * 16 + c];
        u32x4 v1 = inv[ia.y * 16 + c];
        u32x4 v2 = inv[ia.z * 16 + c];
        u32x4 v3 = inv[ia.w * 16 + c];
        u32x4 v4 = inv[ib.x * 16 + c];
        u32x4 v5 = inv[ib.y * 16 + c];
        u32x4 v6 = inv[ib.z * 16 + c];
        u32x4 v7 = inv[ib.w * 16 + c];
        u32x4 v8 = inv[ic.x * 16 + c];
        u32x4 v9 = inv[ic.y * 16 + c];
        u32x4 va = inv[ic.z * 16 + c];
        u32x4 vb = inv[ic.w * 16 + c];
        u32x4 vc = inv[id.x * 16 + c];
        u32x4 vd = inv[id.y * 16 + c];
        u32x4 ve = inv[id.z * 16 + c];
        u32x4 vf = inv[id.w * 16 + c];
        ACC8(v0); ACC8(v1); ACC8(v2); ACC8(v3);
        ACC8(v4); ACC8(v5); ACC8(v6); ACC8(v7);
        ACC8(v8); ACC8(v9); ACC8(va); ACC8(vb);
        ACC8(vc); ACC8(vd); ACC8(ve); ACC8(vf);
    }
#undef ACC8

    u32x4 o;
    o.x = ((unsigned int)f2b(a1) << 16) | f2b(a0);
    o.y = ((unsigned int)f2b(a3) << 16) | f2b(a2);
    o.z = ((unsigned int)f2b(a5) << 16) | f2b(a4);
    o.w = ((unsigned int)f2b(a7) << 16) | f2b(a6);
    *(u32x4*)&aggLDS[nl * LDS_STRIDE + c * 4] = o;   // linear feats: word i = feats 2i,2i+1
    __syncthreads();

    // ---- phase 2: GEMM ----
    int row = c, quad = q;
    int colbase = w * 32;

    f32x4 acc0 = {0.f, 0.f, 0.f, 0.f};
    f32x4 acc1 = {0.f, 0.f, 0.f, 0.f};

    const unsigned int* Al = &aggLDS[row * LDS_STRIDE];
    const short* Xp = (const short*)(in + (nodebase + row) * D);
    const short* W0 = (const short*)(WT + (colbase + row) * 256);
    const short* W1 = (const short*)(WT + (colbase + 16 + row) * 256);

#pragma unroll
    for (int t = 0; t < 4; ++t) {
        bf16x8 af = *(const bf16x8*)(Al + t * 16 + quad * 4);
        int k0 = t * 32 + quad * 8;
        bf16x8 b0 = *(const bf16x8*)(W0 + k0);
        bf16x8 b1 = *(const bf16x8*)(W1 + k0);
        acc0 = __builtin_amdgcn_mfma_f32_16x16x32_bf16(af, b0, acc0, 0, 0, 0);
        acc1 = __builtin_amdgcn_mfma_f32_16x16x32_bf16(af, b1, acc1, 0, 0, 0);
    }
#pragma unroll
    for (int t = 0; t < 4; ++t) {
        int k0 = t * 32 + quad * 8;
        bf16x8 xf = *(const bf16x8*)(Xp + k0);
        bf16x8 b0 = *(const bf16x8*)(W0 + 128 + k0);
        bf16x8 b1 = *(const bf16x8*)(W1 + 128 + k0);
        acc0 = __builtin_amdgcn_mfma_f32_16x16x32_bf16(xf, b0, acc0, 0, 0, 0);
        acc1 = __builtin_amdgcn_mfma_f32_16x16x32_bf16(xf, b1, acc1, 0, 0, 0);
    }

    int c0 = colbase + row, c1 = c0 + 16;
    float bia0 = bias[c0], bia1 = bias[c1];
    float v0[4], v1[4];
#pragma unroll
    for (int r = 0; r < 4; ++r) { v0[r] = acc0[r] + bia0; v1[r] = acc1[r] + bia1; }

    if (outk == nullptr) {
        // layers 0,1: relu + bf16 store
#pragma unroll
        for (int r = 0; r < 4; ++r) {
            int n2 = nodebase + quad * 4 + r;
            out[n2 * D + c0] = f2b(fmaxf(v0[r], 0.f));
            out[n2 * D + c1] = f2b(fmaxf(v1[r], 0.f));
        }
    } else {
        // layer 2: fused global_max_pool (batch sorted)
        int g0 = batch[nodebase];
        int g15 = batch[nodebase + 15];
        if (g0 == g15) {
            float m0 = fmaxf(fmaxf(v0[0], v0[1]), fmaxf(v0[2], v0[3]));
            float m1 = fmaxf(fmaxf(v1[0], v1[1]), fmaxf(v1[2], v1[3]));
            m0 = fmaxf(m0, __shfl_xor(m0, 16)); m0 = fmaxf(m0, __shfl_xor(m0, 32));
            m1 = fmaxf(m1, __shfl_xor(m1, 16)); m1 = fmaxf(m1, __shfl_xor(m1, 32));
            if (quad == 0) {
                atomicMax(&outk[g0 * D + c0], fkey(m0));
                atomicMax(&outk[g0 * D + c1], fkey(m1));
            }
        } else {  // boundary block (~5%): per-value atomics
#pragma unroll
            for (int r = 0; r < 4; ++r) {
                int gg = batch[nodebase + quad * 4 + r];
                atomicMax(&outk[gg * D + c0], fkey(v0[r]));
                atomicMax(&outk[gg * D + c1], fkey(v1[r]));
            }
        }
    }
}

// ---- unmap keys -> floats (in place over d_out) ----------------------------
__global__ void k_unmap(unsigned int* __restrict__ outk) {
    int i = blockIdx.x * 256 + threadIdx.x;   // 64 blocks x 256 = 16384
    unsigned int k = outk[i];
    unsigned int b = (k & 0x80000000u) ? (k ^ 0x80000000u) : ~k;
    ((float*)outk)[i] = __uint_as_float(b);
}

extern "C" void kernel_launch(void* const* d_in, const int* in_sizes, int n_in,
                              void* d_out, int out_size, void* d_ws, size_t ws_size,
                              hipStream_t stream) {
    const float* x = (const float*)d_in[0];
    const int* ei = (const int*)d_in[1];
    const int* batch = (const int*)d_in[2];
    const float* Wrel[3]  = {(const float*)d_in[3], (const float*)d_in[6], (const float*)d_in[9]};
    const float* brel[3]  = {(const float*)d_in[4], (const float*)d_in[7], (const float*)d_in[10]};
    const float* Wroot[3] = {(const float*)d_in[5], (const float*)d_in[8], (const float*)d_in[11]};
    unsigned int* outk = (unsigned int*)d_out;

    char* ws = (char*)d_ws;
    size_t off = 0;
    auto alloc = [&](size_t bytes) -> void* {
        void* p = ws + off;
        off = (off + bytes + 255) & ~(size_t)255;
        return p;
    };
    // activation buffers have one extra zero row (index N_NODES)
    unsigned short* xb  = (unsigned short*)alloc((size_t)(N_NODES + 1) * D * 2);
    unsigned short* hA  = (unsigned short*)alloc((size_t)(N_NODES + 1) * D * 2);
    unsigned short* hB  = (unsigned short*)alloc((size_t)(N_NODES + 1) * D * 2);
    unsigned short* WT  = (unsigned short*)alloc((size_t)3 * 128 * 256 * 2);
    int* rp_pad     = (int*)alloc((size_t)(N_NODES + 1) * 4);
    int* counts     = (int*)alloc((size_t)N_NODES * 4);
    int* cursor     = (int*)alloc((size_t)N_NODES * 4);
    int* src_pad    = (int*)alloc((size_t)(N_EDGES + 16 * N_NODES) * 4);
    int* local_pre  = (int*)alloc((size_t)N_NODES * 4);
    int* blocksums  = (int*)alloc((size_t)SCAN_NBLK * 4);

    // init (zero counts + dummy rows + out keys)
    k_init<<<SCAN_NBLK + 1, 256, 0, stream>>>(batch, counts, xb, hA, hB, outk);
    // packed: hist + x2b + wprep3
    k_pack1<<<5384, 256, 0, stream>>>(ei, counts, x, (unsigned int*)xb,
                                      Wrel[0], Wroot[0], Wrel[1], Wroot[1],
                                      Wrel[2], Wroot[2], WT);
    // scan (padded degrees) + dummy fill + scatter
    k_scan1<<<SCAN_NBLK, 256, 0, stream>>>(counts, local_pre, blocksums);
    k_scan3<<<SCAN_NBLK, 256, 0, stream>>>(local_pre, blocksums, counts,
                                           rp_pad, cursor, src_pad);
    k_scatter<<<(N_EDGES + 255) / 256, 256, 0, stream>>>(ei, cursor, src_pad);

    // 3 fused GraphConv layers; layer 2 folds the global max pool
    k_layer<<<N_NODES / 16, 256, 0, stream>>>(xb, rp_pad, src_pad, WT,
                                              brel[0], hA, batch, nullptr);
    k_layer<<<N_NODES / 16, 256, 0, stream>>>(hA, rp_pad, src_pad, WT + 128 * 256,
                                              brel[1], hB, batch, nullptr);
    k_layer<<<N_NODES / 16, 256, 0, stream>>>(hB, rp_pad, src_pad, WT + 2 * 128 * 256,
                                              brel[2], hB, batch, outk);

    // keys -> floats
    k_unmap<<<N_GRAPHS * D / 256, 256, 0, stream>>>(outk);
}